// Round 5
// baseline (1969.206 us; speedup 1.0000x reference)
//
#include <hip/hip_runtime.h>
#include <cstdint>
#include <cstddef>

typedef unsigned short u16;
typedef __attribute__((ext_vector_type(8))) short short8;
typedef __attribute__((ext_vector_type(4))) float f32x4;

static constexpr int BB = 16, DIN = 240, NN = 2048, TT = 2048;
static constexpr long long Y_SIZE = (long long)BB * DIN * TT;          // 7,864,320 f32
static constexpr float SQRT_HALF_F = 0.70710678118654752440f;
static constexpr int HPAD = 64;                 // zero-pad rows each side of h (max shift 54)
static constexpr int HROWS = NN + 2 * HPAD;     // 2176

#define DEVI __device__ __forceinline__

DEVI u16 f2bf(float f) {
    unsigned u = __builtin_bit_cast(unsigned, f);
    u += 0x7FFFu + ((u >> 16) & 1u);
    return (u16)(u >> 16);
}
DEVI float bf2f(u16 h) {
    unsigned u = ((unsigned)h) << 16;
    return __builtin_bit_cast(float, u);
}

DEVI void gld16(const void* g, const void* l) {
    __builtin_amdgcn_global_load_lds(
        (const __attribute__((address_space(1))) unsigned int*)g,
        (__attribute__((address_space(3))) unsigned int*)l, 16, 0, 0);
}

// GLU column permutation for the 256-wide tile geometry: GEMM col g -> conv output
// channel. Within each wave's 64-col span, fragments n={0,2} are "a" channels and
// n={1,3} the matching gate "b" channels at +16 GEMM cols.
DEVI int glu_perm(int g) {
    int tile = g >> 8, r = g & 255;
    int wcq = r >> 6, r2 = r & 63;
    int n = r2 >> 4, fr = r2 & 15;
    return tile * 128 + wcq * 32 + (n >> 1) * 16 + fr + (n & 1) * 512;
}

// ---------------- GEMM params ----------------
// C[row][col] = scale * sum_taps sum_k A[row+shift][k] * B[col][k]  (+bias)
struct GemmP {
    const u16* A; long long a_bstride; int lda;
    const u16* Bw; long long b_bstride; long long b_tapstride; int ldb;
    int ntaps; int shift0; int dshift; int Kt; int ks_log2;
    void* out; long long o_bstride; int ldc;
    const float* bias; int bias_bstride;
    float scale;
    int store_ncols;
};

#define FENCE() asm volatile("" ::: "memory")
#define SBAR()  do { FENCE(); __builtin_amdgcn_s_barrier(); FENCE(); } while (0)

// =============== 256x256 8-phase MFMA GEMM (BK=64, 8 waves, counted vmcnt) ===============
// OUTK: 1 = bf16 row-major col-bias (+scale). 4 = GLU fused epilogue. 5 = bf16 row-bias.
// Requires tot (= ntaps << ks_log2) EVEN.
template <int OUTK>
__global__ __launch_bounds__(512, 2)
void gemm256(GemmP p, int tilesM, int tilesN) {
    __shared__ __align__(16) u16 As[2][256 * 64];
    __shared__ __align__(16) u16 Bs[2][256 * 64];
    const int tid = threadIdx.x;
    const int lane = tid & 63;
    const int wv = tid >> 6;
    const int wr = wv >> 2, wcq = wv & 3;          // 2M x 4N wave grid
    const int fr = lane & 15, fq = lane >> 4;

    // bijective XCD-aware block swizzle (grid always a multiple of 8)
    const int nwg = gridDim.x;
    int widx = (blockIdx.x & 7) * (nwg >> 3) + (blockIdx.x >> 3);
    const int mt = widx % tilesM; widx /= tilesM;
    const int nt = widx % tilesN;
    const int bz = widx / tilesN;
    const int n0 = mt * 256, c0 = nt * 256;

    const int lda = p.lda, ldb = p.ldb;
    const u16* Abase = p.A + (long long)bz * p.a_bstride;
    const u16* Bbase = p.Bw + (long long)bz * p.b_bstride;
    const int kmask = (1 << p.ks_log2) - 1;
    const int tot = p.ntaps << p.ks_log2;

    f32x4 acc[8][4];
#pragma unroll
    for (int m = 0; m < 8; ++m)
#pragma unroll
        for (int n = 0; n < 4; ++n) acc[m][n] = (f32x4){0.f, 0.f, 0.f, 0.f};

    // ---- staging geometry (per-thread constants) ----
    const int srow = lane >> 3, sslot = lane & 7;
    const int js = (sslot ^ srow) << 3;            // swizzled 16B slot (constant!)
    const int sr0 = wv * 16 + srow;                // first staged row of this thread

    const long long sA8 = 8LL * lda, sAh = 128LL * lda;
    const long long sB8 = 8LL * ldb, sBh = 128LL * ldb;
    const long long dAtap = (long long)p.dshift * lda - (long long)kmask * 64;
    const long long dBtap = p.b_tapstride - (long long)kmask * 64;

    auto aAddr = [&](int t) -> const u16* {
        int tap = t >> p.ks_log2;
        return Abase + (long long)(n0 + p.shift0 + tap * p.dshift + sr0) * lda
               + ((t & kmask) << 6) + js;
    };
    auto bAddr = [&](int t) -> const u16* {
        int tap = t >> p.ks_log2;
        return Bbase + (long long)tap * p.b_tapstride
               + (long long)(c0 + sr0) * ldb + ((t & kmask) << 6) + js;
    };

    // LDS staging bases (wave-uniform; all further offsets are immediates)
    u16* uA = &As[0][wv * 1024];
    u16* uB = &Bs[0][wv * 1024];

    // ---- prologue: A(0), B(0) -> buf0; B(1) -> buf1; counted drain ----
    {
        const u16* a0 = aAddr(0);
        gld16(a0, uA);              gld16(a0 + sA8, uA + 512);
        gld16(a0 + sAh, uA + 8192); gld16(a0 + sAh + sA8, uA + 8192 + 512);
        const u16* b0 = bAddr(0);
        gld16(b0, uB);              gld16(b0 + sB8, uB + 512);
        gld16(b0 + sBh, uB + 8192); gld16(b0 + sBh + sB8, uB + 8192 + 512);
        const u16* b1 = bAddr(1);
        gld16(b1, uB + 16384);              gld16(b1 + sB8, uB + 16384 + 512);
        gld16(b1 + sBh, uB + 16384 + 8192); gld16(b1 + sBh + sB8, uB + 16384 + 8192 + 512);
    }
    const u16* aP = aAddr(1);
    const u16* bP = bAddr(2);
    asm volatile("s_waitcnt vmcnt(4)" ::: "memory");
    __builtin_amdgcn_s_barrier();
    FENCE();

    // ---- fragment-read byte offsets (u16 units; XOR slot folded once) ----
    const int aoff0 = (wr * 128 + fr) * 64 + ((fq ^ (fr & 7)) << 3);
    const int aoff1 = (wr * 128 + fr) * 64 + (((4 + fq) ^ (fr & 7)) << 3);
    const int boff0 = (wcq * 64 + fr) * 64 + ((fq ^ (fr & 7)) << 3);
    const int boff1 = (wcq * 64 + fr) * 64 + (((4 + fq) ^ (fr & 7)) << 3);

    short8 af[4][2], bf0[2][2], bf1[2][2];

#define READ_AQ(MQ)                                                            \
    _Pragma("unroll")                                                          \
    for (int mi = 0; mi < 4; ++mi) {                                           \
        af[mi][0] = *(const short8*)&Ab[aoff0 + ((MQ) * 64 + mi * 16) * 64];   \
        af[mi][1] = *(const short8*)&Ab[aoff1 + ((MQ) * 64 + mi * 16) * 64];   \
    }
#define READ_BQ(BF, NQ)                                                        \
    _Pragma("unroll")                                                          \
    for (int ni = 0; ni < 2; ++ni) {                                           \
        BF[ni][0] = *(const short8*)&Bb[boff0 + ((NQ) * 32 + ni * 16) * 64];   \
        BF[ni][1] = *(const short8*)&Bb[boff1 + ((NQ) * 32 + ni * 16) * 64];   \
    }
#define MFMA_Q(MQ, NQ, BF)                                                     \
    __builtin_amdgcn_s_setprio(1);                                             \
    _Pragma("unroll")                                                          \
    for (int mi = 0; mi < 4; ++mi) {                                           \
        _Pragma("unroll")                                                      \
        for (int ni = 0; ni < 2; ++ni) {                                       \
            _Pragma("unroll")                                                  \
            for (int kk = 0; kk < 2; ++kk)                                     \
                acc[(MQ) * 4 + mi][(NQ) * 2 + ni] =                            \
                    __builtin_amdgcn_mfma_f32_16x16x32_bf16(                   \
                        af[mi][kk], BF[ni][kk],                                \
                        acc[(MQ) * 4 + mi][(NQ) * 2 + ni], 0, 0, 0);           \
        }                                                                      \
    }                                                                          \
    __builtin_amdgcn_s_setprio(0)

// One K-tile: buf BUF_ compile-time; A stages into buf BUF_^1 (tile T_+1),
// B stages into buf BUF_ (tile T_+2). PA_/PB_ predicates; STEPA_/STEPB_ advances.
#define TILEBODY(BUF_, PA_, PB_, STEPA_, STEPB_)                               \
  {                                                                            \
    const u16* Ab = &As[BUF_][0];                                              \
    const u16* Bb = &Bs[BUF_][0];                                              \
    /* phase 1: quad m0n0; stage A-half0 */                                    \
    READ_AQ(0);                                                                \
    READ_BQ(bf0, 0);                                                           \
    if (PA_) { gld16(aP, uA + ((BUF_) ^ 1) * 16384);                           \
               gld16(aP + sA8, uA + ((BUF_) ^ 1) * 16384 + 512); }             \
    SBAR();                                                                    \
    MFMA_Q(0, 0, bf0);                                                         \
    SBAR();                                                                    \
    /* phase 2: quad m0n1; stage A-half1 */                                    \
    READ_BQ(bf1, 1);                                                           \
    if (PA_) { gld16(aP + sAh, uA + ((BUF_) ^ 1) * 16384 + 8192);              \
               gld16(aP + sAh + sA8, uA + ((BUF_) ^ 1) * 16384 + 8192 + 512);  \
               aP += (STEPA_); }                                               \
    SBAR();                                                                    \
    MFMA_Q(0, 1, bf1);                                                         \
    SBAR();                                                                    \
    /* phase 3: quad m1n1; stage B-half0 */                                    \
    READ_AQ(1);                                                                \
    if (PB_) { gld16(bP, uB + (BUF_) * 16384);                                 \
               gld16(bP + sB8, uB + (BUF_) * 16384 + 512); }                   \
    SBAR();                                                                    \
    MFMA_Q(1, 1, bf1);                                                         \
    SBAR();                                                                    \
    /* phase 4: quad m1n0 (regs only); stage B-half1; counted drain */         \
    if (PB_) { gld16(bP + sBh, uB + (BUF_) * 16384 + 8192);                    \
               gld16(bP + sBh + sB8, uB + (BUF_) * 16384 + 8192 + 512);        \
               bP += (STEPB_); }                                               \
    SBAR();                                                                    \
    MFMA_Q(1, 0, bf0);                                                         \
    asm volatile("s_waitcnt vmcnt(4)" ::: "memory");                           \
    SBAR();                                                                    \
  }

    for (int t = 0; t < tot; t += 2) {
        const long long stA1 = (((t + 2) & kmask) != 0) ? 64 : dAtap;
        const long long stA2 = (((t + 3) & kmask) != 0) ? 64 : dAtap;
        const long long stB1 = (((t + 3) & kmask) != 0) ? 64 : dBtap;
        const long long stB2 = (((t + 4) & kmask) != 0) ? 64 : dBtap;
        const bool pB1 = (t + 2) < tot;
        const bool pA2 = (t + 2) < tot;
        const bool pB2 = (t + 3) < tot;
        TILEBODY(0, true, pB1, stA1, stB1);
        TILEBODY(1, pA2, pB2, stA2, stB2);
    }
#undef READ_AQ
#undef READ_BQ
#undef MFMA_Q
#undef TILEBODY

    if constexpr (OUTK == 4) {
        // GLU: a,b pairs in adjacent 16-col fragments; residual h_in via A operand.
        const float* bp = p.bias;
#pragma unroll
        for (int m = 0; m < 8; ++m) {
#pragma unroll
            for (int pr = 0; pr < 2; ++pr) {
                int ca = c0 + wcq * 64 + (2 * pr) * 16 + fr;
                int chan = (c0 >> 1) + wcq * 32 + pr * 16 + fr;
                float biasa = bp[ca], biasb = bp[ca + 16];
#pragma unroll
                for (int r = 0; r < 4; ++r) {
                    int row = n0 + wr * 128 + m * 16 + fq * 4 + r;
                    float a = acc[m][2 * pr][r] + biasa;
                    float bq = acc[m][2 * pr + 1][r] + biasb;
                    float sig = 1.f / (1.f + __expf(-bq));
                    float h = bf2f(Abase[(long long)row * lda + chan]);
                    ((u16*)p.out)[(long long)bz * p.o_bstride + (long long)row * p.ldc + chan]
                        = f2bf((h + a * sig) * SQRT_HALF_F);
                }
            }
        }
        return;
    } else {
        const float* bias = p.bias ? p.bias + (long long)bz * p.bias_bstride : nullptr;
#pragma unroll
        for (int m = 0; m < 8; ++m) {
#pragma unroll
            for (int n = 0; n < 4; ++n) {
                int col = c0 + wcq * 64 + n * 16 + fr;
                float cb = (OUTK == 1 && bias) ? bias[col] : 0.f;
#pragma unroll
                for (int r = 0; r < 4; ++r) {
                    int row = n0 + wr * 128 + m * 16 + fq * 4 + r;
                    float v = acc[m][n][r] * p.scale + cb;
                    if (OUTK == 5) v += bias[row];
                    ((u16*)p.out)[(long long)bz * p.o_bstride + (long long)row * p.ldc + col]
                        = f2bf(v);
                }
            }
        }
    }
}

// =============== 128x128 GEMM (kept for the N=240 transposed-f32 post GEMM) ===============
template <int OUTK>
__global__ __launch_bounds__(256, 2)
void gemm_kernel(GemmP p) {
    __shared__ u16 As[128 * 64];
    __shared__ u16 Bs[128 * 64];
    const int tid = threadIdx.x;
    const int lane = tid & 63, wv = tid >> 6;
    const int wr = wv >> 1, wc = wv & 1;
    const int bz = blockIdx.z;
    const int n0 = blockIdx.x * 128;
    const int c0 = blockIdx.y * 128;
    const u16* Abase = p.A + (long long)bz * p.a_bstride;
    const u16* Bbase = p.Bw + (long long)bz * p.b_bstride;

    f32x4 acc[4][4];
#pragma unroll
    for (int i = 0; i < 4; ++i)
#pragma unroll
        for (int j = 0; j < 4; ++j) acc[i][j] = (f32x4){0.f, 0.f, 0.f, 0.f};

    const int ksteps = p.Kt >> 6;
    const int tot = p.ntaps * ksteps;
    const int srow = lane >> 3;
    const int scol = (lane & 7) * 8;
    const int fr = lane & 15;
    const int fk = (lane >> 4) * 8;

    for (int t = 0; t < tot; ++t) {
        const int tap = t / ksteps;
        const int ks = (t - tap * ksteps) << 6;
        const int shift = p.shift0 + tap * p.dshift;
        __syncthreads();
        {
            const u16* asrc = Abase + (long long)(n0 + shift) * p.lda + ks;
#pragma unroll
            for (int c = 0; c < 4; ++c) {
                int chunk = wv * 4 + c;
                int row = chunk * 8 + srow;
                gld16(asrc + (long long)row * p.lda + scol, &As[chunk * 512]);
            }
            const u16* bsrc = Bbase + (long long)tap * p.b_tapstride + (long long)c0 * p.ldb + ks;
#pragma unroll
            for (int c = 0; c < 4; ++c) {
                int chunk = wv * 4 + c;
                int row = chunk * 8 + srow;
                gld16(bsrc + (long long)row * p.ldb + scol, &Bs[chunk * 512]);
            }
        }
        asm volatile("s_waitcnt vmcnt(0)" ::: "memory");
        __syncthreads();
#pragma unroll
        for (int kk = 0; kk < 2; ++kk) {
            short8 af[4], bfr[4];
#pragma unroll
            for (int m = 0; m < 4; ++m) {
                int arow = wr * 64 + m * 16 + fr;
                af[m] = *(const short8*)&As[arow * 64 + kk * 32 + fk];
            }
#pragma unroll
            for (int nn2 = 0; nn2 < 4; ++nn2) {
                int brow = wc * 64 + nn2 * 16 + fr;
                bfr[nn2] = *(const short8*)&Bs[brow * 64 + kk * 32 + fk];
            }
#pragma unroll
            for (int m = 0; m < 4; ++m)
#pragma unroll
                for (int nn2 = 0; nn2 < 4; ++nn2)
                    acc[m][nn2] = __builtin_amdgcn_mfma_f32_16x16x32_bf16(
                        af[m], bfr[nn2], acc[m][nn2], 0, 0, 0);
        }
    }

    const float* bias = p.bias ? p.bias + (long long)bz * p.bias_bstride : nullptr;
#pragma unroll
    for (int m = 0; m < 4; ++m) {
#pragma unroll
        for (int nn2 = 0; nn2 < 4; ++nn2) {
#pragma unroll
            for (int r = 0; r < 4; ++r) {
                int row = n0 + wr * 64 + m * 16 + ((lane >> 4) << 2) + r;
                int col = c0 + wc * 64 + nn2 * 16 + (lane & 15);
                if (col >= p.store_ncols) continue;
                float v = acc[m][nn2][r] * p.scale;
                if (bias) v += bias[col];
                long long off = (OUTK == 0 || OUTK == 1)
                                    ? (long long)row * p.ldc + col
                                    : (long long)col * p.ldc + row;
                long long idx = (long long)bz * p.o_bstride + off;
                if (OUTK == 0 || OUTK == 2) ((float*)p.out)[idx] = v;
                else ((u16*)p.out)[idx] = f2bf(v);
            }
        }
    }
}

// ---------------- elementwise / helper kernels ----------------

__global__ void cvt_glu(const float* src, u16* dst) {
    long long t = (long long)blockIdx.x * blockDim.x + threadIdx.x;
    const long long total = 8LL * 5 * 1024 * 512;
    if (t >= total) return;
    int i = (int)(t % 512); long long r = t / 512;
    int g = (int)(r % 1024); r /= 1024;
    int k = (int)(r % 5); int l = (int)(r / 5);
    int o = glu_perm(g);
    dst[t] = f2bf(src[(((long long)l * 1024 + o) * 512 + i) * 5 + k]);
}

__global__ void perm_bias(const float* gb, float* biasP) {
    int t = blockIdx.x * 256 + threadIdx.x;
    if (t >= 8 * 1024) return;
    int g = t & 1023, l = t >> 10;
    biasP[t] = gb[l * 1024 + glu_perm(g)];
}

__global__ void cvt_pad(const float* src, u16* dst, int Os, int Is, int Od, int Id) {
    long long t = (long long)blockIdx.x * blockDim.x + threadIdx.x;
    if (t >= (long long)Od * Id) return;
    int i = (int)(t % Id); int o = (int)(t / Id);
    float v = (o < Os && i < Is) ? src[(long long)o * Is + i] : 0.f;
    dst[t] = f2bf(v);
}

// src [b][Csrc][Len] f32 -> dst [b][Len][Cdst] bf16 (zero-pad channels)
__global__ void transpose_in(const float* src, u16* dst, int Csrc, int Cdst, int Len) {
    __shared__ float tile[32][33];
    int b = blockIdx.z;
    int n0 = blockIdx.x * 32, c0 = blockIdx.y * 32;
    int tx = threadIdx.x, ty = threadIdx.y;
    int c = c0 + ty, n = n0 + tx;
    float v = 0.f;
    if (c < Csrc) v = src[((long long)b * Csrc + c) * Len + n];
    tile[ty][tx] = v;
    __syncthreads();
    dst[((long long)b * Len + (n0 + ty)) * Cdst + (c0 + tx)] = f2bf(tile[tx][ty]);
}

__global__ void zero_pads(u16* h) {
    long long t = (long long)blockIdx.x * blockDim.x + threadIdx.x;
    const long long total = (long long)BB * 128 * 512;
    if (t >= total) return;
    int c = (int)(t % 512); long long r = t / 512;
    int rr = (int)(r % 128); int b = (int)(r / 128);
    int row = rr < HPAD ? rr : (HROWS - 128 + rr);
    h[((long long)b * HROWS + row) * 512 + c] = 0;
}

__global__ void prebias_kernel(const float* ct, const float* wcpre, const float* wpre,
                               const float* bpre, float* qbias) {
    __shared__ float s[240];
    int b = blockIdx.x; int tid = threadIdx.x;
    if (tid < 240) {
        float a = 0.f;
        for (int c = 0; c < 8; ++c) a += ct[b * 8 + c] * wcpre[c * 240 + tid];
        s[tid] = a;
    }
    __syncthreads();
    for (int o = tid; o < 512; o += 256) {
        float a = bpre[o];
        for (int d0 = 0; d0 < 240; ++d0) a += wpre[o * 240 + d0] * s[d0];
        qbias[b * 512 + o] = a;
    }
}

__global__ void postbias_kernel(const float* ct, const float* wcpost, const float* wpost,
                                const float* bpost, float* ybias) {
    __shared__ float s[1024];
    int b = blockIdx.x; int tid = threadIdx.x;
    for (int e = tid; e < 1024; e += 256) {
        float a = 0.f;
        for (int c = 0; c < 8; ++c) a += ct[b * 8 + c] * wcpost[c * 1024 + e];
        s[e] = a;
    }
    __syncthreads();
    if (tid < 240) {
        float a = bpost[tid];
        for (int e = 0; e < 1024; ++e) a += wpost[tid * 1024 + e] * s[e];
        ybias[b * 240 + tid] = a;
    }
}

// One wave per (b,t): read bf16 score row, softmax, write normalized bf16 AT row.
__global__ __launch_bounds__(256)
void softmax_rows(const u16* St, u16* AT) {
    int b = blockIdx.y;
    int t = blockIdx.x * 4 + (threadIdx.x >> 6);
    int lane = threadIdx.x & 63;
    const u16* row = St + ((long long)b * TT + t) * NN;
    short8 v[4];
#pragma unroll
    for (int i = 0; i < 4; ++i) v[i] = ((const short8*)row)[i * 64 + lane];
    float f[32];
#pragma unroll
    for (int i = 0; i < 4; ++i)
#pragma unroll
        for (int j = 0; j < 8; ++j) f[i * 8 + j] = bf2f((u16)v[i][j]);
    float m = -3.4e38f;
#pragma unroll
    for (int i = 0; i < 32; ++i) m = fmaxf(m, f[i]);
#pragma unroll
    for (int s = 1; s < 64; s <<= 1) m = fmaxf(m, __shfl_xor(m, s, 64));
    float sum = 0.f;
#pragma unroll
    for (int i = 0; i < 32; ++i) { f[i] = __expf(f[i] - m); sum += f[i]; }
#pragma unroll
    for (int s = 1; s < 64; s <<= 1) sum += __shfl_xor(sum, s, 64);
    float li = 1.f / sum;
    u16* atrow = AT + ((long long)b * TT + t) * NN;
#pragma unroll
    for (int i = 0; i < 4; ++i) {
        short8 pk;
#pragma unroll
        for (int j = 0; j < 8; ++j) pk[j] = (short)f2bf(f[i * 8 + j] * li);
        ((short8*)atrow)[i * 64 + lane] = pk;
    }
}

// AT bf16 [b][t][n] -> A f32 [b][n][t] (final output region)
__global__ void transpose_out(const u16* AT, float* A) {
    __shared__ float tile[32][33];
    int b = blockIdx.z;
    int n0 = blockIdx.x * 32, t0 = blockIdx.y * 32;
    int tx = threadIdx.x, ty = threadIdx.y;
#pragma unroll
    for (int k = 0; k < 4; ++k) {
        int t = t0 + ty + k * 8;
        tile[ty + k * 8][tx] = bf2f(AT[((long long)b * TT + t) * NN + n0 + tx]);
    }
    __syncthreads();
#pragma unroll
    for (int k = 0; k < 4; ++k) {
        int n = n0 + ty + k * 8;
        A[((long long)b * NN + n) * TT + t0 + tx] = tile[tx][ty + k * 8];
    }
}

// ---------------- host orchestration ----------------

extern "C" void kernel_launch(void* const* d_in, const int* in_sizes, int n_in,
                              void* d_out, int out_size, void* d_ws, size_t ws_size,
                              hipStream_t stream) {
    const float* in_s        = (const float*)d_in[0];
    const float* in_t        = (const float*)d_in[1];
    const float* c_t         = (const float*)d_in[2];
    const float* enc_start_w = (const float*)d_in[3];
    const float* enc_start_b = (const float*)d_in[4];
    const float* glu_w       = (const float*)d_in[5];
    const float* glu_b       = (const float*)d_in[6];
    const float* enc_end_w   = (const float*)d_in[7];
    const float* enc_end_b   = (const float*)d_in[8];
    const float* wc_pre      = (const float*)d_in[9];
    const float* w_pre       = (const float*)d_in[10];
    const float* b_pre       = (const float*)d_in[11];
    const float* wc_post     = (const float*)d_in[12];
    const float* w_post      = (const float*)d_in[13];
    const float* b_post      = (const float*)d_in[14];

    // workspace layout
    char* w = (char*)d_ws;
    u16* wglu   = (u16*)w; w += 8LL * 5 * 1024 * 512 * 2;
    u16* wstart = (u16*)w; w += 512LL * 256 * 2;
    u16* wend   = (u16*)w; w += 1024LL * 512 * 2;
    u16* wpre   = (u16*)w; w += 512LL * 256 * 2;
    u16* wpost  = (u16*)w; w += 256LL * 1024 * 2;
    u16* XS     = (u16*)w; w += (long long)BB * NN * 256 * 2;
    u16* XT     = (u16*)w; w += (long long)BB * TT * 256 * 2;
    u16* h0     = (u16*)w; w += (long long)BB * HROWS * 512 * 2;
    u16* h1     = (u16*)w; w += (long long)BB * HROWS * 512 * 2;
    u16* Kb     = (u16*)w; w += (long long)BB * NN * 512 * 2;
    u16* Vb     = (u16*)w; w += (long long)BB * 512 * NN * 2;
    u16* Rc     = (u16*)w; w += (long long)BB * TT * 1024 * 2;
    u16* ATb    = (u16*)w; w += (long long)BB * TT * NN * 2;
    float* qbias = (float*)w; w += 16LL * 512 * 4;
    float* ybias = (float*)w; w += 16LL * 256 * 4;
    float* biasP = (float*)w; w += 8LL * 1024 * 4;
    if ((size_t)(w - (char*)d_ws) > ws_size) return;  // insufficient scratch — bail

    float* yout = (float*)d_out;
    float* Areg = yout + Y_SIZE;       // final A f32 [b][n][t]
    u16* Sbf = (u16*)Areg;             // transient bf16 scores [b][t][n]

    // ---- conversions / setup ----
    cvt_glu<<<(8LL * 5 * 1024 * 512 + 255) / 256, 256, 0, stream>>>(glu_w, wglu);
    perm_bias<<<(8 * 1024 + 255) / 256, 256, 0, stream>>>(glu_b, biasP);
    cvt_pad<<<(512 * 256 + 255) / 256, 256, 0, stream>>>(enc_start_w, wstart, 512, 240, 512, 256);
    cvt_pad<<<(1024 * 512 + 255) / 256, 256, 0, stream>>>(enc_end_w, wend, 1024, 512, 1024, 512);
    cvt_pad<<<(512 * 256 + 255) / 256, 256, 0, stream>>>(w_pre, wpre, 512, 240, 512, 256);
    cvt_pad<<<(256 * 1024 + 255) / 256, 256, 0, stream>>>(w_post, wpost, 240, 1024, 256, 1024);
    transpose_in<<<dim3(NN / 32, 256 / 32, BB), dim3(32, 32), 0, stream>>>(in_s, XS, 240, 256, NN);
    transpose_in<<<dim3(TT / 32, 256 / 32, BB), dim3(32, 32), 0, stream>>>(in_t, XT, 240, 256, TT);
    zero_pads<<<((long long)BB * 128 * 512 + 255) / 256, 256, 0, stream>>>(h0);
    zero_pads<<<((long long)BB * 128 * 512 + 255) / 256, 256, 0, stream>>>(h1);
    prebias_kernel<<<16, 256, 0, stream>>>(c_t, wc_pre, w_pre, b_pre, qbias);
    postbias_kernel<<<16, 256, 0, stream>>>(c_t, wc_post, w_post, b_post, ybias);

    // ---- enc_start: XS[2048][256] x wstart[512][256] -> h0 bf16 [n][512] ----
    {
        GemmP p{}; p.A = XS; p.a_bstride = (long long)NN * 256; p.lda = 256;
        p.Bw = wstart; p.b_bstride = 0; p.b_tapstride = 0; p.ldb = 256;
        p.ntaps = 1; p.shift0 = 0; p.dshift = 0; p.Kt = 256; p.ks_log2 = 2;
        p.out = h0 + HPAD * 512; p.o_bstride = (long long)HROWS * 512; p.ldc = 512;
        p.bias = enc_start_b; p.bias_bstride = 0; p.scale = 1.f; p.store_ncols = 512;
        gemm256<1><<<8 * 2 * 16, 512, 0, stream>>>(p, 8, 2);
    }

    // ---- 8 GLU blocks (fused epilogue) ----
    const int dils[8] = {1, 3, 9, 27, 1, 3, 9, 27};
    u16* hin = h0; u16* hout = h1;
    for (int l = 0; l < 8; ++l) {
        GemmP q{}; q.A = hin + HPAD * 512; q.a_bstride = (long long)HROWS * 512; q.lda = 512;
        q.Bw = wglu + (long long)l * 5 * 1024 * 512; q.b_bstride = 0;
        q.b_tapstride = 1024LL * 512; q.ldb = 512;
        q.ntaps = 5; q.shift0 = -2 * dils[l]; q.dshift = dils[l]; q.Kt = 512; q.ks_log2 = 3;
        q.out = hout + HPAD * 512; q.o_bstride = (long long)HROWS * 512; q.ldc = 512;
        q.bias = biasP + l * 1024; q.bias_bstride = 0; q.scale = 1.f; q.store_ncols = 1024;
        gemm256<4><<<8 * 4 * 16, 512, 0, stream>>>(q, 8, 4);
        u16* tmp = hin; hin = hout; hout = tmp;
    }

    // ---- enc_end K: h[n][512] x wend_K[512][512] -> Kb bf16 [n][512] ----
    {
        GemmP p{}; p.A = hin + HPAD * 512; p.a_bstride = (long long)HROWS * 512; p.lda = 512;
        p.Bw = wend; p.b_bstride = 0; p.b_tapstride = 0; p.ldb = 512;
        p.ntaps = 1; p.shift0 = 0; p.dshift = 0; p.Kt = 512; p.ks_log2 = 3;
        p.out = Kb; p.o_bstride = (long long)NN * 512; p.ldc = 512;
        p.bias = enc_end_b; p.bias_bstride = 0; p.scale = 1.f; p.store_ncols = 512;
        gemm256<1><<<8 * 2 * 16, 512, 0, stream>>>(p, 8, 2);
    }
    // ---- enc_end V (operand-swapped): Vb[d][n] = wend_V[d][k] · h[n][k], row-bias ----
    {
        GemmP p{}; p.A = wend + 512LL * 512; p.a_bstride = 0; p.lda = 512;
        p.Bw = hin + HPAD * 512; p.b_bstride = (long long)HROWS * 512; p.b_tapstride = 0; p.ldb = 512;
        p.ntaps = 1; p.shift0 = 0; p.dshift = 0; p.Kt = 512; p.ks_log2 = 3;
        p.out = Vb; p.o_bstride = 512LL * NN; p.ldc = NN;
        p.bias = enc_end_b + 512; p.bias_bstride = 0; p.scale = 1.f; p.store_ncols = NN;
        gemm256<5><<<2 * 8 * 16, 512, 0, stream>>>(p, 2, 8);
    }

    // ---- pre-decoder: Q into Rc columns 512..1023 ----
    {
        GemmP p{}; p.A = XT; p.a_bstride = (long long)TT * 256; p.lda = 256;
        p.Bw = wpre; p.b_bstride = 0; p.b_tapstride = 0; p.ldb = 256;
        p.ntaps = 1; p.shift0 = 0; p.dshift = 0; p.Kt = 256; p.ks_log2 = 2;
        p.out = Rc + 512; p.o_bstride = (long long)TT * 1024; p.ldc = 1024;
        p.bias = qbias; p.bias_bstride = 512; p.scale = 1.f; p.store_ncols = 512;
        gemm256<1><<<8 * 2 * 16, 512, 0, stream>>>(p, 8, 2);
    }

    // ---- scores: St[t][n] = Q[t]·K[n] / sqrt(d), bf16 into Sbf ----
    {
        GemmP p{}; p.A = Rc + 512; p.a_bstride = (long long)TT * 1024; p.lda = 1024;
        p.Bw = Kb; p.b_bstride = (long long)NN * 512; p.b_tapstride = 0; p.ldb = 512;
        p.ntaps = 1; p.shift0 = 0; p.dshift = 0; p.Kt = 512; p.ks_log2 = 3;
        p.out = Sbf; p.o_bstride = (long long)TT * NN; p.ldc = NN;
        p.bias = nullptr; p.bias_bstride = 0; p.scale = 0.04419417382415922f; // 1/sqrt(512)
        p.store_ncols = NN;
        gemm256<1><<<8 * 8 * 16, 512, 0, stream>>>(p, 8, 8);
    }

    // ---- softmax over n (contiguous), normalized AT bf16 ----
    softmax_rows<<<dim3(TT / 4, BB), 256, 0, stream>>>(Sbf, ATb);
    // ---- AT -> final A f32 [n][t] (overwrites dead Sbf region) ----
    transpose_out<<<dim3(NN / 32, TT / 32, BB), dim3(32, 8), 0, stream>>>(ATb, Areg);

    // ---- R = V x A  (C[t][d] = sum_n AT[t][n] * V[d][n]) into Rc cols 0..511 ----
    {
        GemmP p{}; p.A = ATb; p.a_bstride = (long long)TT * NN; p.lda = NN;
        p.Bw = Vb; p.b_bstride = 512LL * NN; p.b_tapstride = 0; p.ldb = NN;
        p.ntaps = 1; p.shift0 = 0; p.dshift = 0; p.Kt = NN; p.ks_log2 = 5;
        p.out = Rc; p.o_bstride = (long long)TT * 1024; p.ldc = 1024;
        p.bias = nullptr; p.bias_bstride = 0; p.scale = 1.f; p.store_ncols = 512;
        gemm256<1><<<8 * 2 * 16, 512, 0, stream>>>(p, 8, 2);
    }

    // ---- post-decoder: Rc[t][1024] x wpost -> y f32 [b][240][t] (transposed store) ----
    {
        GemmP p{}; p.A = Rc; p.a_bstride = (long long)TT * 1024; p.lda = 1024;
        p.Bw = wpost; p.b_bstride = 0; p.b_tapstride = 0; p.ldb = 1024;
        p.ntaps = 1; p.shift0 = 0; p.dshift = 0; p.Kt = 1024; p.ks_log2 = 4;
        p.out = yout; p.o_bstride = (long long)DIN * TT; p.ldc = TT;
        p.bias = ybias; p.bias_bstride = 240; p.scale = 1.f; p.store_ncols = 240;
        gemm_kernel<2><<<dim3(16, 2, 16), 256, 0, stream>>>(p);
    }
}

// Round 6
// 1866.237 us; speedup vs baseline: 1.0552x; 1.0552x over previous
//
#include <hip/hip_runtime.h>
#include <cstdint>
#include <cstddef>

typedef unsigned short u16;
typedef __attribute__((ext_vector_type(8))) short short8;
typedef __attribute__((ext_vector_type(4))) float f32x4;

static constexpr int BB = 16, DIN = 240, NN = 2048, TT = 2048;
static constexpr long long Y_SIZE = (long long)BB * DIN * TT;          // 7,864,320 f32
static constexpr float SQRT_HALF_F = 0.70710678118654752440f;
static constexpr int HPAD = 64;                 // zero-pad rows each side of h (max shift 54)
static constexpr int HROWS = NN + 2 * HPAD;     // 2176

#define DEVI __device__ __forceinline__

DEVI u16 f2bf(float f) {
    unsigned u = __builtin_bit_cast(unsigned, f);
    u += 0x7FFFu + ((u >> 16) & 1u);
    return (u16)(u >> 16);
}
DEVI float bf2f(u16 h) {
    unsigned u = ((unsigned)h) << 16;
    return __builtin_bit_cast(float, u);
}

DEVI void gld16(const void* g, const void* l) {
    __builtin_amdgcn_global_load_lds(
        (const __attribute__((address_space(1))) unsigned int*)g,
        (__attribute__((address_space(3))) unsigned int*)l, 16, 0, 0);
}

// GLU column permutation for the 256-wide tile geometry: GEMM col g -> conv output
// channel. Within each wave's 64-col span, fragments n={0,2} are "a" channels and
// n={1,3} the matching gate "b" channels at +16 GEMM cols.
DEVI int glu_perm(int g) {
    int tile = g >> 8, r = g & 255;
    int wcq = r >> 6, r2 = r & 63;
    int n = r2 >> 4, fr = r2 & 15;
    return tile * 128 + wcq * 32 + (n >> 1) * 16 + fr + (n & 1) * 512;
}

// ---------------- GEMM params ----------------
// C[row][col] = scale * sum_taps sum_k A[row+shift][k] * B[col][k]  (+bias)
struct GemmP {
    const u16* A; long long a_bstride; int lda;
    const u16* Bw; long long b_bstride; long long b_tapstride; int ldb;
    int ntaps; int shift0; int dshift; int Kt; int ks_log2;
    void* out; long long o_bstride; int ldc;
    const float* bias; int bias_bstride;
    float scale;
    int store_ncols;
};

#define FENCE() asm volatile("" ::: "memory")
#define SBAR()  do { FENCE(); __builtin_amdgcn_s_barrier(); FENCE(); } while (0)
// rule-18 pattern: after barrier, wait own LDS reads, pin schedule
#define PH_WAIT() do { asm volatile("s_waitcnt lgkmcnt(0)" ::: "memory"); \
                       __builtin_amdgcn_sched_barrier(0); } while (0)

// =============== 256x256 8-phase MFMA GEMM (BK=64, 8 waves, counted vmcnt) ===============
// OUTK: 1 = bf16 row-major col-bias (+scale). 4 = GLU fused epilogue. 5 = bf16 row-bias.
// Requires tot (= ntaps << ks_log2) EVEN and >= 4.
template <int OUTK>
__global__ __launch_bounds__(512, 2)
void gemm256(GemmP p, int tilesM, int tilesN) {
    __shared__ __align__(16) u16 As[2][256 * 64];
    __shared__ __align__(16) u16 Bs[2][256 * 64];
    const int tid = threadIdx.x;
    const int lane = tid & 63;
    const int wv = tid >> 6;
    const int wr = wv >> 2, wcq = wv & 3;          // 2M x 4N wave grid
    const int fr = lane & 15, fq = lane >> 4;

    // bijective XCD-aware block swizzle (grid always a multiple of 8)
    const int nwg = gridDim.x;
    int widx = (blockIdx.x & 7) * (nwg >> 3) + (blockIdx.x >> 3);
    const int mt = widx % tilesM; widx /= tilesM;
    const int nt = widx % tilesN;
    const int bz = widx / tilesN;
    const int n0 = mt * 256, c0 = nt * 256;

    const int lda = p.lda, ldb = p.ldb;
    const u16* Abase = p.A + (long long)bz * p.a_bstride;
    const u16* Bbase = p.Bw + (long long)bz * p.b_bstride;
    const int kmask = (1 << p.ks_log2) - 1;
    const int tot = p.ntaps << p.ks_log2;

    f32x4 acc[8][4];
#pragma unroll
    for (int m = 0; m < 8; ++m)
#pragma unroll
        for (int n = 0; n < 4; ++n) acc[m][n] = (f32x4){0.f, 0.f, 0.f, 0.f};

    // ---- staging geometry (per-thread constants) ----
    const int srow = lane >> 3, sslot = lane & 7;
    const int js = (sslot ^ srow) << 3;            // swizzled 16B slot (constant!)
    const int sr0 = wv * 16 + srow;                // first staged row of this thread

    const long long sA8 = 8LL * lda, sAh = 128LL * lda;
    const long long sB8 = 8LL * ldb, sBh = 128LL * ldb;
    const long long dAtap = (long long)p.dshift * lda - (long long)kmask * 64;
    const long long dBtap = p.b_tapstride - (long long)kmask * 64;

    auto aAddr = [&](int t) -> const u16* {
        int tap = t >> p.ks_log2;
        return Abase + (long long)(n0 + p.shift0 + tap * p.dshift + sr0) * lda
               + ((t & kmask) << 6) + js;
    };
    auto bAddr = [&](int t) -> const u16* {
        int tap = t >> p.ks_log2;
        return Bbase + (long long)tap * p.b_tapstride
               + (long long)(c0 + sr0) * ldb + ((t & kmask) << 6) + js;
    };

    // LDS staging bases (wave-uniform; all further offsets are immediates)
    u16* uA = &As[0][wv * 1024];
    u16* uB = &Bs[0][wv * 1024];

    // ---- prologue: A(0), B(0) -> buf0; B(1) -> buf1; counted drain ----
    {
        const u16* a0 = aAddr(0);
        gld16(a0, uA);              gld16(a0 + sA8, uA + 512);
        gld16(a0 + sAh, uA + 8192); gld16(a0 + sAh + sA8, uA + 8192 + 512);
        const u16* b0 = bAddr(0);
        gld16(b0, uB);              gld16(b0 + sB8, uB + 512);
        gld16(b0 + sBh, uB + 8192); gld16(b0 + sBh + sB8, uB + 8192 + 512);
        const u16* b1 = bAddr(1);
        gld16(b1, uB + 16384);              gld16(b1 + sB8, uB + 16384 + 512);
        gld16(b1 + sBh, uB + 16384 + 8192); gld16(b1 + sBh + sB8, uB + 16384 + 8192 + 512);
    }
    const u16* aP = aAddr(1);
    const u16* bP = bAddr(2);
    asm volatile("s_waitcnt vmcnt(4)" ::: "memory");
    __builtin_amdgcn_s_barrier();
    FENCE();

    // ---- fragment-read byte offsets (u16 units; XOR slot folded once) ----
    const int aoff0 = (wr * 128 + fr) * 64 + ((fq ^ (fr & 7)) << 3);
    const int aoff1 = (wr * 128 + fr) * 64 + (((4 + fq) ^ (fr & 7)) << 3);
    const int boff0 = (wcq * 64 + fr) * 64 + ((fq ^ (fr & 7)) << 3);
    const int boff1 = (wcq * 64 + fr) * 64 + (((4 + fq) ^ (fr & 7)) << 3);

    short8 af[4][2], bf0[2][2], bf1[2][2];

#define READ_AQ(MQ)                                                            \
    _Pragma("unroll")                                                          \
    for (int mi = 0; mi < 4; ++mi) {                                           \
        af[mi][0] = *(const short8*)&Ab[aoff0 + ((MQ) * 64 + mi * 16) * 64];   \
        af[mi][1] = *(const short8*)&Ab[aoff1 + ((MQ) * 64 + mi * 16) * 64];   \
    }
#define READ_BQ(BF, NQ)                                                        \
    _Pragma("unroll")                                                          \
    for (int ni = 0; ni < 2; ++ni) {                                           \
        BF[ni][0] = *(const short8*)&Bb[boff0 + ((NQ) * 32 + ni * 16) * 64];   \
        BF[ni][1] = *(const short8*)&Bb[boff1 + ((NQ) * 32 + ni * 16) * 64];   \
    }
#define MFMA_Q(MQ, NQ, BF)                                                     \
    __builtin_amdgcn_s_setprio(1);                                             \
    _Pragma("unroll")                                                          \
    for (int mi = 0; mi < 4; ++mi) {                                           \
        _Pragma("unroll")                                                      \
        for (int ni = 0; ni < 2; ++ni) {                                       \
            _Pragma("unroll")                                                  \
            for (int kk = 0; kk < 2; ++kk)                                     \
                acc[(MQ) * 4 + mi][(NQ) * 2 + ni] =                            \
                    __builtin_amdgcn_mfma_f32_16x16x32_bf16(                   \
                        af[mi][kk], BF[ni][kk],                                \
                        acc[(MQ) * 4 + mi][(NQ) * 2 + ni], 0, 0, 0);           \
        }                                                                      \
    }                                                                          \
    __builtin_amdgcn_s_setprio(0)

// One K-tile: buf BUF_ compile-time; A stages into buf BUF_^1 (tile T+1),
// B stages into buf BUF_ (tile T+2). DO_A_/DO_B_ are LITERAL 0/1.
// VM_: 4 = vmcnt(4), 0 = vmcnt(0), -1 = none.
#define TILEBODY(BUF_, DO_A_, DO_B_, STEPA_, STEPB_, VM_)                      \
  {                                                                            \
    const u16* Ab = &As[BUF_][0];                                              \
    const u16* Bb = &Bs[BUF_][0];                                              \
    /* phase 1: quad m0n0; stage A-half0 */                                    \
    READ_AQ(0);                                                                \
    READ_BQ(bf0, 0);                                                           \
    if (DO_A_) { gld16(aP, uA + ((BUF_) ^ 1) * 16384);                         \
                 gld16(aP + sA8, uA + ((BUF_) ^ 1) * 16384 + 512); }           \
    SBAR();                                                                    \
    PH_WAIT();                                                                 \
    MFMA_Q(0, 0, bf0);                                                         \
    SBAR();                                                                    \
    /* phase 2: quad m0n1; stage A-half1 */                                    \
    READ_BQ(bf1, 1);                                                           \
    if (DO_A_) { gld16(aP + sAh, uA + ((BUF_) ^ 1) * 16384 + 8192);            \
                 gld16(aP + sAh + sA8, uA + ((BUF_) ^ 1) * 16384 + 8192 + 512);\
                 aP += (STEPA_); }                                             \
    SBAR();                                                                    \
    PH_WAIT();                                                                 \
    MFMA_Q(0, 1, bf1);                                                         \
    SBAR();                                                                    \
    /* phase 3: quad m1n1; stage B-half0 */                                    \
    READ_AQ(1);                                                                \
    if (DO_B_) { gld16(bP, uB + (BUF_) * 16384);                               \
                 gld16(bP + sB8, uB + (BUF_) * 16384 + 512); }                 \
    SBAR();                                                                    \
    PH_WAIT();                                                                 \
    MFMA_Q(1, 1, bf1);                                                         \
    SBAR();                                                                    \
    /* phase 4: quad m1n0 (regs only); stage B-half1; counted drain */         \
    if (DO_B_) { gld16(bP + sBh, uB + (BUF_) * 16384 + 8192);                  \
                 gld16(bP + sBh + sB8, uB + (BUF_) * 16384 + 8192 + 512);      \
                 bP += (STEPB_); }                                             \
    SBAR();                                                                    \
    MFMA_Q(1, 0, bf0);                                                         \
    if ((VM_) == 4) asm volatile("s_waitcnt vmcnt(4)" ::: "memory");           \
    else if ((VM_) == 0) asm volatile("s_waitcnt vmcnt(0)" ::: "memory");      \
    SBAR();                                                                    \
  }

    // main loop: unconditional staging (valid while t+3 <= tot-1)
    int t = 0;
    for (; t + 3 < tot; t += 2) {
        const long long stA1 = (((t + 2) & kmask) != 0) ? 64 : dAtap;
        const long long stA2 = (((t + 3) & kmask) != 0) ? 64 : dAtap;
        const long long stB1 = (((t + 3) & kmask) != 0) ? 64 : dBtap;
        const long long stB2 = (((t + 4) & kmask) != 0) ? 64 : dBtap;
        TILEBODY(0, 1, 1, stA1, stB1, 4);
        TILEBODY(1, 1, 1, stA2, stB2, 4);
    }
    // epilogue pair: tile tot-2 (stage A(tot-1) only, full drain), tile tot-1
    TILEBODY(0, 1, 0, 0, 0, 0);
    TILEBODY(1, 0, 0, 0, 0, -1);
#undef READ_AQ
#undef READ_BQ
#undef MFMA_Q
#undef TILEBODY

    if constexpr (OUTK == 4) {
        // GLU: a,b pairs in adjacent 16-col fragments; residual h_in via A operand.
        const float* bp = p.bias;
#pragma unroll
        for (int m = 0; m < 8; ++m) {
#pragma unroll
            for (int pr = 0; pr < 2; ++pr) {
                int ca = c0 + wcq * 64 + (2 * pr) * 16 + fr;
                int chan = (c0 >> 1) + wcq * 32 + pr * 16 + fr;
                float biasa = bp[ca], biasb = bp[ca + 16];
#pragma unroll
                for (int r = 0; r < 4; ++r) {
                    int row = n0 + wr * 128 + m * 16 + fq * 4 + r;
                    float a = acc[m][2 * pr][r] + biasa;
                    float bq = acc[m][2 * pr + 1][r] + biasb;
                    float sig = 1.f / (1.f + __expf(-bq));
                    float h = bf2f(Abase[(long long)row * lda + chan]);
                    ((u16*)p.out)[(long long)bz * p.o_bstride + (long long)row * p.ldc + chan]
                        = f2bf((h + a * sig) * SQRT_HALF_F);
                }
            }
        }
        return;
    } else {
        const float* bias = p.bias ? p.bias + (long long)bz * p.bias_bstride : nullptr;
#pragma unroll
        for (int m = 0; m < 8; ++m) {
#pragma unroll
            for (int n = 0; n < 4; ++n) {
                int col = c0 + wcq * 64 + n * 16 + fr;
                float cb = (OUTK == 1 && bias) ? bias[col] : 0.f;
#pragma unroll
                for (int r = 0; r < 4; ++r) {
                    int row = n0 + wr * 128 + m * 16 + fq * 4 + r;
                    float v = acc[m][n][r] * p.scale + cb;
                    if (OUTK == 5) v += bias[row];
                    ((u16*)p.out)[(long long)bz * p.o_bstride + (long long)row * p.ldc + col]
                        = f2bf(v);
                }
            }
        }
    }
}

// =============== 128x128 GEMM (kept for the N=240 transposed-f32 post GEMM) ===============
template <int OUTK>
__global__ __launch_bounds__(256, 2)
void gemm_kernel(GemmP p) {
    __shared__ u16 As[128 * 64];
    __shared__ u16 Bs[128 * 64];
    const int tid = threadIdx.x;
    const int lane = tid & 63, wv = tid >> 6;
    const int wr = wv >> 1, wc = wv & 1;
    const int bz = blockIdx.z;
    const int n0 = blockIdx.x * 128;
    const int c0 = blockIdx.y * 128;
    const u16* Abase = p.A + (long long)bz * p.a_bstride;
    const u16* Bbase = p.Bw + (long long)bz * p.b_bstride;

    f32x4 acc[4][4];
#pragma unroll
    for (int i = 0; i < 4; ++i)
#pragma unroll
        for (int j = 0; j < 4; ++j) acc[i][j] = (f32x4){0.f, 0.f, 0.f, 0.f};

    const int ksteps = p.Kt >> 6;
    const int tot = p.ntaps * ksteps;
    const int srow = lane >> 3;
    const int scol = (lane & 7) * 8;
    const int fr = lane & 15;
    const int fk = (lane >> 4) * 8;

    for (int t = 0; t < tot; ++t) {
        const int tap = t / ksteps;
        const int ks = (t - tap * ksteps) << 6;
        const int shift = p.shift0 + tap * p.dshift;
        __syncthreads();
        {
            const u16* asrc = Abase + (long long)(n0 + shift) * p.lda + ks;
#pragma unroll
            for (int c = 0; c < 4; ++c) {
                int chunk = wv * 4 + c;
                int row = chunk * 8 + srow;
                gld16(asrc + (long long)row * p.lda + scol, &As[chunk * 512]);
            }
            const u16* bsrc = Bbase + (long long)tap * p.b_tapstride + (long long)c0 * p.ldb + ks;
#pragma unroll
            for (int c = 0; c < 4; ++c) {
                int chunk = wv * 4 + c;
                int row = chunk * 8 + srow;
                gld16(bsrc + (long long)row * p.ldb + scol, &Bs[chunk * 512]);
            }
        }
        asm volatile("s_waitcnt vmcnt(0)" ::: "memory");
        __syncthreads();
#pragma unroll
        for (int kk = 0; kk < 2; ++kk) {
            short8 af[4], bfr[4];
#pragma unroll
            for (int m = 0; m < 4; ++m) {
                int arow = wr * 64 + m * 16 + fr;
                af[m] = *(const short8*)&As[arow * 64 + kk * 32 + fk];
            }
#pragma unroll
            for (int nn2 = 0; nn2 < 4; ++nn2) {
                int brow = wc * 64 + nn2 * 16 + fr;
                bfr[nn2] = *(const short8*)&Bs[brow * 64 + kk * 32 + fk];
            }
#pragma unroll
            for (int m = 0; m < 4; ++m)
#pragma unroll
                for (int nn2 = 0; nn2 < 4; ++nn2)
                    acc[m][nn2] = __builtin_amdgcn_mfma_f32_16x16x32_bf16(
                        af[m], bfr[nn2], acc[m][nn2], 0, 0, 0);
        }
    }

    const float* bias = p.bias ? p.bias + (long long)bz * p.bias_bstride : nullptr;
#pragma unroll
    for (int m = 0; m < 4; ++m) {
#pragma unroll
        for (int nn2 = 0; nn2 < 4; ++nn2) {
#pragma unroll
            for (int r = 0; r < 4; ++r) {
                int row = n0 + wr * 64 + m * 16 + ((lane >> 4) << 2) + r;
                int col = c0 + wc * 64 + nn2 * 16 + (lane & 15);
                if (col >= p.store_ncols) continue;
                float v = acc[m][nn2][r] * p.scale;
                if (bias) v += bias[col];
                long long off = (OUTK == 0 || OUTK == 1)
                                    ? (long long)row * p.ldc + col
                                    : (long long)col * p.ldc + row;
                long long idx = (long long)bz * p.o_bstride + off;
                if (OUTK == 0 || OUTK == 2) ((float*)p.out)[idx] = v;
                else ((u16*)p.out)[idx] = f2bf(v);
            }
        }
    }
}

// ---------------- elementwise / helper kernels ----------------

__global__ void cvt_glu(const float* src, u16* dst) {
    long long t = (long long)blockIdx.x * blockDim.x + threadIdx.x;
    const long long total = 8LL * 5 * 1024 * 512;
    if (t >= total) return;
    int i = (int)(t % 512); long long r = t / 512;
    int g = (int)(r % 1024); r /= 1024;
    int k = (int)(r % 5); int l = (int)(r / 5);
    int o = glu_perm(g);
    dst[t] = f2bf(src[(((long long)l * 1024 + o) * 512 + i) * 5 + k]);
}

__global__ void perm_bias(const float* gb, float* biasP) {
    int t = blockIdx.x * 256 + threadIdx.x;
    if (t >= 8 * 1024) return;
    int g = t & 1023, l = t >> 10;
    biasP[t] = gb[l * 1024 + glu_perm(g)];
}

__global__ void cvt_pad(const float* src, u16* dst, int Os, int Is, int Od, int Id) {
    long long t = (long long)blockIdx.x * blockDim.x + threadIdx.x;
    if (t >= (long long)Od * Id) return;
    int i = (int)(t % Id); int o = (int)(t / Id);
    float v = (o < Os && i < Is) ? src[(long long)o * Is + i] : 0.f;
    dst[t] = f2bf(v);
}

// src [b][Csrc][Len] f32 -> dst [b][Len][Cdst] bf16 (zero-pad channels)
__global__ void transpose_in(const float* src, u16* dst, int Csrc, int Cdst, int Len) {
    __shared__ float tile[32][33];
    int b = blockIdx.z;
    int n0 = blockIdx.x * 32, c0 = blockIdx.y * 32;
    int tx = threadIdx.x, ty = threadIdx.y;
    int c = c0 + ty, n = n0 + tx;
    float v = 0.f;
    if (c < Csrc) v = src[((long long)b * Csrc + c) * Len + n];
    tile[ty][tx] = v;
    __syncthreads();
    dst[((long long)b * Len + (n0 + ty)) * Cdst + (c0 + tx)] = f2bf(tile[tx][ty]);
}

__global__ void zero_pads(u16* h) {
    long long t = (long long)blockIdx.x * blockDim.x + threadIdx.x;
    const long long total = (long long)BB * 128 * 512;
    if (t >= total) return;
    int c = (int)(t % 512); long long r = t / 512;
    int rr = (int)(r % 128); int b = (int)(r / 128);
    int row = rr < HPAD ? rr : (HROWS - 128 + rr);
    h[((long long)b * HROWS + row) * 512 + c] = 0;
}

__global__ void prebias_kernel(const float* ct, const float* wcpre, const float* wpre,
                               const float* bpre, float* qbias) {
    __shared__ float s[240];
    int b = blockIdx.x; int tid = threadIdx.x;
    if (tid < 240) {
        float a = 0.f;
        for (int c = 0; c < 8; ++c) a += ct[b * 8 + c] * wcpre[c * 240 + tid];
        s[tid] = a;
    }
    __syncthreads();
    for (int o = tid; o < 512; o += 256) {
        float a = bpre[o];
        for (int d0 = 0; d0 < 240; ++d0) a += wpre[o * 240 + d0] * s[d0];
        qbias[b * 512 + o] = a;
    }
}

__global__ void postbias_kernel(const float* ct, const float* wcpost, const float* wpost,
                                const float* bpost, float* ybias) {
    __shared__ float s[1024];
    int b = blockIdx.x; int tid = threadIdx.x;
    for (int e = tid; e < 1024; e += 256) {
        float a = 0.f;
        for (int c = 0; c < 8; ++c) a += ct[b * 8 + c] * wcpost[c * 1024 + e];
        s[e] = a;
    }
    __syncthreads();
    if (tid < 240) {
        float a = bpost[tid];
        for (int e = 0; e < 1024; ++e) a += wpost[tid * 1024 + e] * s[e];
        ybias[b * 240 + tid] = a;
    }
}

// One wave per (b,t): read bf16 score row, softmax, write normalized bf16 AT row.
__global__ __launch_bounds__(256)
void softmax_rows(const u16* St, u16* AT) {
    int b = blockIdx.y;
    int t = blockIdx.x * 4 + (threadIdx.x >> 6);
    int lane = threadIdx.x & 63;
    const u16* row = St + ((long long)b * TT + t) * NN;
    short8 v[4];
#pragma unroll
    for (int i = 0; i < 4; ++i) v[i] = ((const short8*)row)[i * 64 + lane];
    float f[32];
#pragma unroll
    for (int i = 0; i < 4; ++i)
#pragma unroll
        for (int j = 0; j < 8; ++j) f[i * 8 + j] = bf2f((u16)v[i][j]);
    float m = -3.4e38f;
#pragma unroll
    for (int i = 0; i < 32; ++i) m = fmaxf(m, f[i]);
#pragma unroll
    for (int s = 1; s < 64; s <<= 1) m = fmaxf(m, __shfl_xor(m, s, 64));
    float sum = 0.f;
#pragma unroll
    for (int i = 0; i < 32; ++i) { f[i] = __expf(f[i] - m); sum += f[i]; }
#pragma unroll
    for (int s = 1; s < 64; s <<= 1) sum += __shfl_xor(sum, s, 64);
    float li = 1.f / sum;
    u16* atrow = AT + ((long long)b * TT + t) * NN;
#pragma unroll
    for (int i = 0; i < 4; ++i) {
        short8 pk;
#pragma unroll
        for (int j = 0; j < 8; ++j) pk[j] = (short)f2bf(f[i * 8 + j] * li);
        ((short8*)atrow)[i * 64 + lane] = pk;
    }
}

// AT bf16 [b][t][n] -> A f32 [b][n][t] (final output region)
__global__ void transpose_out(const u16* AT, float* A) {
    __shared__ float tile[32][33];
    int b = blockIdx.z;
    int n0 = blockIdx.x * 32, t0 = blockIdx.y * 32;
    int tx = threadIdx.x, ty = threadIdx.y;
#pragma unroll
    for (int k = 0; k < 4; ++k) {
        int t = t0 + ty + k * 8;
        tile[ty + k * 8][tx] = bf2f(AT[((long long)b * TT + t) * NN + n0 + tx]);
    }
    __syncthreads();
#pragma unroll
    for (int k = 0; k < 4; ++k) {
        int n = n0 + ty + k * 8;
        A[((long long)b * NN + n) * TT + t0 + tx] = tile[tx][ty + k * 8];
    }
}

// ---------------- host orchestration ----------------

extern "C" void kernel_launch(void* const* d_in, const int* in_sizes, int n_in,
                              void* d_out, int out_size, void* d_ws, size_t ws_size,
                              hipStream_t stream) {
    const float* in_s        = (const float*)d_in[0];
    const float* in_t        = (const float*)d_in[1];
    const float* c_t         = (const float*)d_in[2];
    const float* enc_start_w = (const float*)d_in[3];
    const float* enc_start_b = (const float*)d_in[4];
    const float* glu_w       = (const float*)d_in[5];
    const float* glu_b       = (const float*)d_in[6];
    const float* enc_end_w   = (const float*)d_in[7];
    const float* enc_end_b   = (const float*)d_in[8];
    const float* wc_pre      = (const float*)d_in[9];
    const float* w_pre       = (const float*)d_in[10];
    const float* b_pre       = (const float*)d_in[11];
    const float* wc_post     = (const float*)d_in[12];
    const float* w_post      = (const float*)d_in[13];
    const float* b_post      = (const float*)d_in[14];

    // workspace layout
    char* w = (char*)d_ws;
    u16* wglu   = (u16*)w; w += 8LL * 5 * 1024 * 512 * 2;
    u16* wstart = (u16*)w; w += 512LL * 256 * 2;
    u16* wend   = (u16*)w; w += 1024LL * 512 * 2;
    u16* wpre   = (u16*)w; w += 512LL * 256 * 2;
    u16* wpost  = (u16*)w; w += 256LL * 1024 * 2;
    u16* XS     = (u16*)w; w += (long long)BB * NN * 256 * 2;
    u16* XT     = (u16*)w; w += (long long)BB * TT * 256 * 2;
    u16* h0     = (u16*)w; w += (long long)BB * HROWS * 512 * 2;
    u16* h1     = (u16*)w; w += (long long)BB * HROWS * 512 * 2;
    u16* Kb     = (u16*)w; w += (long long)BB * NN * 512 * 2;
    u16* Vb     = (u16*)w; w += (long long)BB * 512 * NN * 2;
    u16* Rc     = (u16*)w; w += (long long)BB * TT * 1024 * 2;
    u16* ATb    = (u16*)w; w += (long long)BB * TT * NN * 2;
    float* qbias = (float*)w; w += 16LL * 512 * 4;
    float* ybias = (float*)w; w += 16LL * 256 * 4;
    float* biasP = (float*)w; w += 8LL * 1024 * 4;
    if ((size_t)(w - (char*)d_ws) > ws_size) return;  // insufficient scratch — bail

    float* yout = (float*)d_out;
    float* Areg = yout + Y_SIZE;       // final A f32 [b][n][t]
    u16* Sbf = (u16*)Areg;             // transient bf16 scores [b][t][n]

    // ---- conversions / setup ----
    cvt_glu<<<(8LL * 5 * 1024 * 512 + 255) / 256, 256, 0, stream>>>(glu_w, wglu);
    perm_bias<<<(8 * 1024 + 255) / 256, 256, 0, stream>>>(glu_b, biasP);
    cvt_pad<<<(512 * 256 + 255) / 256, 256, 0, stream>>>(enc_start_w, wstart, 512, 240, 512, 256);
    cvt_pad<<<(1024 * 512 + 255) / 256, 256, 0, stream>>>(enc_end_w, wend, 1024, 512, 1024, 512);
    cvt_pad<<<(512 * 256 + 255) / 256, 256, 0, stream>>>(w_pre, wpre, 512, 240, 512, 256);
    cvt_pad<<<(256 * 1024 + 255) / 256, 256, 0, stream>>>(w_post, wpost, 240, 1024, 256, 1024);
    transpose_in<<<dim3(NN / 32, 256 / 32, BB), dim3(32, 32), 0, stream>>>(in_s, XS, 240, 256, NN);
    transpose_in<<<dim3(TT / 32, 256 / 32, BB), dim3(32, 32), 0, stream>>>(in_t, XT, 240, 256, TT);
    zero_pads<<<((long long)BB * 128 * 512 + 255) / 256, 256, 0, stream>>>(h0);
    zero_pads<<<((long long)BB * 128 * 512 + 255) / 256, 256, 0, stream>>>(h1);
    prebias_kernel<<<16, 256, 0, stream>>>(c_t, wc_pre, w_pre, b_pre, qbias);
    postbias_kernel<<<16, 256, 0, stream>>>(c_t, wc_post, w_post, b_post, ybias);

    // ---- enc_start: XS[2048][256] x wstart[512][256] -> h0 bf16 [n][512] ----
    {
        GemmP p{}; p.A = XS; p.a_bstride = (long long)NN * 256; p.lda = 256;
        p.Bw = wstart; p.b_bstride = 0; p.b_tapstride = 0; p.ldb = 256;
        p.ntaps = 1; p.shift0 = 0; p.dshift = 0; p.Kt = 256; p.ks_log2 = 2;
        p.out = h0 + HPAD * 512; p.o_bstride = (long long)HROWS * 512; p.ldc = 512;
        p.bias = enc_start_b; p.bias_bstride = 0; p.scale = 1.f; p.store_ncols = 512;
        gemm256<1><<<8 * 2 * 16, 512, 0, stream>>>(p, 8, 2);
    }

    // ---- 8 GLU blocks (fused epilogue) ----
    const int dils[8] = {1, 3, 9, 27, 1, 3, 9, 27};
    u16* hin = h0; u16* hout = h1;
    for (int l = 0; l < 8; ++l) {
        GemmP q{}; q.A = hin + HPAD * 512; q.a_bstride = (long long)HROWS * 512; q.lda = 512;
        q.Bw = wglu + (long long)l * 5 * 1024 * 512; q.b_bstride = 0;
        q.b_tapstride = 1024LL * 512; q.ldb = 512;
        q.ntaps = 5; q.shift0 = -2 * dils[l]; q.dshift = dils[l]; q.Kt = 512; q.ks_log2 = 3;
        q.out = hout + HPAD * 512; q.o_bstride = (long long)HROWS * 512; q.ldc = 512;
        q.bias = biasP + l * 1024; q.bias_bstride = 0; q.scale = 1.f; q.store_ncols = 1024;
        gemm256<4><<<8 * 4 * 16, 512, 0, stream>>>(q, 8, 4);
        u16* tmp = hin; hin = hout; hout = tmp;
    }

    // ---- enc_end K: h[n][512] x wend_K[512][512] -> Kb bf16 [n][512] ----
    {
        GemmP p{}; p.A = hin + HPAD * 512; p.a_bstride = (long long)HROWS * 512; p.lda = 512;
        p.Bw = wend; p.b_bstride = 0; p.b_tapstride = 0; p.ldb = 512;
        p.ntaps = 1; p.shift0 = 0; p.dshift = 0; p.Kt = 512; p.ks_log2 = 3;
        p.out = Kb; p.o_bstride = (long long)NN * 512; p.ldc = 512;
        p.bias = enc_end_b; p.bias_bstride = 0; p.scale = 1.f; p.store_ncols = 512;
        gemm256<1><<<8 * 2 * 16, 512, 0, stream>>>(p, 8, 2);
    }
    // ---- enc_end V (operand-swapped): Vb[d][n] = wend_V[d][k] · h[n][k], row-bias ----
    {
        GemmP p{}; p.A = wend + 512LL * 512; p.a_bstride = 0; p.lda = 512;
        p.Bw = hin + HPAD * 512; p.b_bstride = (long long)HROWS * 512; p.b_tapstride = 0; p.ldb = 512;
        p.ntaps = 1; p.shift0 = 0; p.dshift = 0; p.Kt = 512; p.ks_log2 = 3;
        p.out = Vb; p.o_bstride = 512LL * NN; p.ldc = NN;
        p.bias = enc_end_b + 512; p.bias_bstride = 0; p.scale = 1.f; p.store_ncols = NN;
        gemm256<5><<<2 * 8 * 16, 512, 0, stream>>>(p, 2, 8);
    }

    // ---- pre-decoder: Q into Rc columns 512..1023 ----
    {
        GemmP p{}; p.A = XT; p.a_bstride = (long long)TT * 256; p.lda = 256;
        p.Bw = wpre; p.b_bstride = 0; p.b_tapstride = 0; p.ldb = 256;
        p.ntaps = 1; p.shift0 = 0; p.dshift = 0; p.Kt = 256; p.ks_log2 = 2;
        p.out = Rc + 512; p.o_bstride = (long long)TT * 1024; p.ldc = 1024;
        p.bias = qbias; p.bias_bstride = 512; p.scale = 1.f; p.store_ncols = 512;
        gemm256<1><<<8 * 2 * 16, 512, 0, stream>>>(p, 8, 2);
    }

    // ---- scores: St[t][n] = Q[t]·K[n] / sqrt(d), bf16 into Sbf ----
    {
        GemmP p{}; p.A = Rc + 512; p.a_bstride = (long long)TT * 1024; p.lda = 1024;
        p.Bw = Kb; p.b_bstride = (long long)NN * 512; p.b_tapstride = 0; p.ldb = 512;
        p.ntaps = 1; p.shift0 = 0; p.dshift = 0; p.Kt = 512; p.ks_log2 = 3;
        p.out = Sbf; p.o_bstride = (long long)TT * NN; p.ldc = NN;
        p.bias = nullptr; p.bias_bstride = 0; p.scale = 0.04419417382415922f; // 1/sqrt(512)
        p.store_ncols = NN;
        gemm256<1><<<8 * 8 * 16, 512, 0, stream>>>(p, 8, 8);
    }

    // ---- softmax over n (contiguous), normalized AT bf16 ----
    softmax_rows<<<dim3(TT / 4, BB), 256, 0, stream>>>(Sbf, ATb);
    // ---- AT -> final A f32 [n][t] (overwrites dead Sbf region) ----
    transpose_out<<<dim3(NN / 32, TT / 32, BB), dim3(32, 8), 0, stream>>>(ATb, Areg);

    // ---- R = V x A  (C[t][d] = sum_n AT[t][n] * V[d][n]) into Rc cols 0..511 ----
    {
        GemmP p{}; p.A = ATb; p.a_bstride = (long long)TT * NN; p.lda = NN;
        p.Bw = Vb; p.b_bstride = 512LL * NN; p.b_tapstride = 0; p.ldb = NN;
        p.ntaps = 1; p.shift0 = 0; p.dshift = 0; p.Kt = NN; p.ks_log2 = 5;
        p.out = Rc; p.o_bstride = (long long)TT * 1024; p.ldc = 1024;
        p.bias = nullptr; p.bias_bstride = 0; p.scale = 1.f; p.store_ncols = 512;
        gemm256<1><<<8 * 2 * 16, 512, 0, stream>>>(p, 8, 2);
    }

    // ---- post-decoder: Rc[t][1024] x wpost -> y f32 [b][240][t] (transposed store) ----
    {
        GemmP p{}; p.A = Rc; p.a_bstride = (long long)TT * 1024; p.lda = 1024;
        p.Bw = wpost; p.b_bstride = 0; p.b_tapstride = 0; p.ldb = 1024;
        p.ntaps = 1; p.shift0 = 0; p.dshift = 0; p.Kt = 1024; p.ks_log2 = 4;
        p.out = yout; p.o_bstride = (long long)DIN * TT; p.ldc = TT;
        p.bias = ybias; p.bias_bstride = 240; p.scale = 1.f; p.store_ncols = 240;
        gemm_kernel<2><<<dim3(16, 2, 16), 256, 0, stream>>>(p);
    }
}

// Round 7
// 1779.909 us; speedup vs baseline: 1.1064x; 1.0485x over previous
//
#include <hip/hip_runtime.h>
#include <cstdint>
#include <cstddef>

typedef unsigned short u16;
typedef __attribute__((ext_vector_type(8))) short short8;
typedef __attribute__((ext_vector_type(4))) float f32x4;

static constexpr int BB = 16, DIN = 240, NN = 2048, TT = 2048;
static constexpr long long Y_SIZE = (long long)BB * DIN * TT;          // 7,864,320 f32
static constexpr float SQRT_HALF_F = 0.70710678118654752440f;
static constexpr int HPAD = 64;                 // zero-pad rows each side of h (max shift 54)
static constexpr int HROWS = NN + 2 * HPAD;     // 2176

#define DEVI __device__ __forceinline__

DEVI u16 f2bf(float f) {
    unsigned u = __builtin_bit_cast(unsigned, f);
    u += 0x7FFFu + ((u >> 16) & 1u);
    return (u16)(u >> 16);
}
DEVI float bf2f(u16 h) {
    unsigned u = ((unsigned)h) << 16;
    return __builtin_bit_cast(float, u);
}

DEVI void gld16(const void* g, const void* l) {
    __builtin_amdgcn_global_load_lds(
        (const __attribute__((address_space(1))) unsigned int*)g,
        (__attribute__((address_space(3))) unsigned int*)l, 16, 0, 0);
}

// GLU column permutation for the 256-wide tile geometry: GEMM col g -> conv output
// channel. Within each wave's 64-col span, fragments n={0,2} are "a" channels and
// n={1,3} the matching gate "b" channels at +16 GEMM cols.
DEVI int glu_perm(int g) {
    int tile = g >> 8, r = g & 255;
    int wcq = r >> 6, r2 = r & 63;
    int n = r2 >> 4, fr = r2 & 15;
    return tile * 128 + wcq * 32 + (n >> 1) * 16 + fr + (n & 1) * 512;
}

// ---------------- GEMM params ----------------
// C[row][col] = scale * sum_taps sum_k A[row+shift][k] * B[col][k]  (+bias)
struct GemmP {
    const u16* A; long long a_bstride; int lda;
    const u16* Bw; long long b_bstride; long long b_tapstride; int ldb;
    int ntaps; int shift0; int dshift; int Kt; int ks_log2;
    void* out; long long o_bstride; int ldc;
    const float* bias; int bias_bstride;
    float scale;
    int store_ncols;
};

#define FENCE() asm volatile("" ::: "memory")
#define SBAR()  do { FENCE(); __builtin_amdgcn_s_barrier(); FENCE(); } while (0)

// =============== 256x256 MFMA GEMM, 2-barrier K-tile, counted vmcnt ===============
// OUTK: 1 = bf16 row-major col-bias (+scale). 2 = f32 transposed col-bias, col-masked.
//       4 = GLU fused epilogue. 5 = bf16 row-bias.
// Requires tot (= ntaps << ks_log2) EVEN and >= 4.
//
// Hazard audit for the 2-barrier scheme (waves may drift inside regions):
//  - A(t+1) staging writes As[buf^1]; tile t-1's A-reads from As[buf^1] completed
//    before each wave's t-1 end-barrier (values consumed by its ph3/ph4 MFMAs). OK.
//  - B(t+2) staging writes Bs[buf]; all waves' B(t)-reads from Bs[buf] completed
//    before mid-barrier (values consumed by ph1/ph2 MFMAs in region A). OK.
//  - Tile t+1 reads need A(t+1)/B(t+1) staging landed: vmcnt(4) at end of tile t
//    leaves only the 4 newest (B(t+2)) outstanding, then end-barrier. OK.
template <int OUTK>
__global__ __launch_bounds__(512, 2)
void gemm256(GemmP p, int tilesM, int tilesN) {
    __shared__ __align__(16) u16 As[2][256 * 64];
    __shared__ __align__(16) u16 Bs[2][256 * 64];
    const int tid = threadIdx.x;
    const int lane = tid & 63;
    const int wv = tid >> 6;
    const int wr = wv >> 2, wcq = wv & 3;          // 2M x 4N wave grid
    const int fr = lane & 15, fq = lane >> 4;

    // bijective XCD-aware block swizzle (grid always a multiple of 8)
    const int nwg = gridDim.x;
    int widx = (blockIdx.x & 7) * (nwg >> 3) + (blockIdx.x >> 3);
    const int mt = widx % tilesM; widx /= tilesM;
    const int nt = widx % tilesN;
    const int bz = widx / tilesN;
    const int n0 = mt * 256, c0 = nt * 256;

    const int lda = p.lda, ldb = p.ldb;
    const u16* Abase = p.A + (long long)bz * p.a_bstride;
    const u16* Bbase = p.Bw + (long long)bz * p.b_bstride;
    const int kmask = (1 << p.ks_log2) - 1;
    const int tot = p.ntaps << p.ks_log2;

    f32x4 acc[8][4];
#pragma unroll
    for (int m = 0; m < 8; ++m)
#pragma unroll
        for (int n = 0; n < 4; ++n) acc[m][n] = (f32x4){0.f, 0.f, 0.f, 0.f};

    // ---- staging geometry (per-thread constants) ----
    const int srow = lane >> 3, sslot = lane & 7;
    const int js = (sslot ^ srow) << 3;            // swizzled 16B slot (constant!)
    const int sr0 = wv * 16 + srow;                // first staged row of this thread

    const long long sA8 = 8LL * lda, sAh = 128LL * lda;
    const long long sB8 = 8LL * ldb, sBh = 128LL * ldb;
    const long long dAtap = (long long)p.dshift * lda - (long long)kmask * 64;
    const long long dBtap = p.b_tapstride - (long long)kmask * 64;

    auto aAddr = [&](int t) -> const u16* {
        int tap = t >> p.ks_log2;
        return Abase + (long long)(n0 + p.shift0 + tap * p.dshift + sr0) * lda
               + ((t & kmask) << 6) + js;
    };
    auto bAddr = [&](int t) -> const u16* {
        int tap = t >> p.ks_log2;
        return Bbase + (long long)tap * p.b_tapstride
               + (long long)(c0 + sr0) * ldb + ((t & kmask) << 6) + js;
    };

    // LDS staging bases (wave-uniform; all further offsets are immediates)
    u16* uA = &As[0][wv * 1024];
    u16* uB = &Bs[0][wv * 1024];

    // ---- prologue: A(0), B(0) -> buf0; B(1) -> buf1; counted drain ----
    {
        const u16* a0 = aAddr(0);
        gld16(a0, uA);              gld16(a0 + sA8, uA + 512);
        gld16(a0 + sAh, uA + 8192); gld16(a0 + sAh + sA8, uA + 8192 + 512);
        const u16* b0 = bAddr(0);
        gld16(b0, uB);              gld16(b0 + sB8, uB + 512);
        gld16(b0 + sBh, uB + 8192); gld16(b0 + sBh + sB8, uB + 8192 + 512);
        const u16* b1 = bAddr(1);
        gld16(b1, uB + 16384);              gld16(b1 + sB8, uB + 16384 + 512);
        gld16(b1 + sBh, uB + 16384 + 8192); gld16(b1 + sBh + sB8, uB + 16384 + 8192 + 512);
    }
    const u16* aP = aAddr(1);
    const u16* bP = bAddr(2);
    asm volatile("s_waitcnt vmcnt(4)" ::: "memory");
    __builtin_amdgcn_s_barrier();
    FENCE();

    // ---- fragment-read byte offsets (u16 units; XOR slot folded once) ----
    const int aoff0 = (wr * 128 + fr) * 64 + ((fq ^ (fr & 7)) << 3);
    const int aoff1 = (wr * 128 + fr) * 64 + (((4 + fq) ^ (fr & 7)) << 3);
    const int boff0 = (wcq * 64 + fr) * 64 + ((fq ^ (fr & 7)) << 3);
    const int boff1 = (wcq * 64 + fr) * 64 + (((4 + fq) ^ (fr & 7)) << 3);

    short8 af0[4][2], af1[4][2], bf0[2][2], bf1[2][2];

#define READ_AQ(DEST, MQ)                                                      \
    _Pragma("unroll")                                                          \
    for (int mi = 0; mi < 4; ++mi) {                                           \
        DEST[mi][0] = *(const short8*)&Ab[aoff0 + ((MQ) * 64 + mi * 16) * 64]; \
        DEST[mi][1] = *(const short8*)&Ab[aoff1 + ((MQ) * 64 + mi * 16) * 64]; \
    }
#define READ_BQ(BF, NQ)                                                        \
    _Pragma("unroll")                                                          \
    for (int ni = 0; ni < 2; ++ni) {                                           \
        BF[ni][0] = *(const short8*)&Bb[boff0 + ((NQ) * 32 + ni * 16) * 64];   \
        BF[ni][1] = *(const short8*)&Bb[boff1 + ((NQ) * 32 + ni * 16) * 64];   \
    }
#define MFMA_Q2(MQ, NQ, AF, BF)                                                \
    __builtin_amdgcn_s_setprio(1);                                             \
    _Pragma("unroll")                                                          \
    for (int mi = 0; mi < 4; ++mi) {                                           \
        _Pragma("unroll")                                                      \
        for (int ni = 0; ni < 2; ++ni) {                                       \
            _Pragma("unroll")                                                  \
            for (int kk = 0; kk < 2; ++kk)                                     \
                acc[(MQ) * 4 + mi][(NQ) * 2 + ni] =                            \
                    __builtin_amdgcn_mfma_f32_16x16x32_bf16(                   \
                        AF[mi][kk], BF[ni][kk],                                \
                        acc[(MQ) * 4 + mi][(NQ) * 2 + ni], 0, 0, 0);           \
        }                                                                      \
    }                                                                          \
    __builtin_amdgcn_s_setprio(0)

// One K-tile, 2 barriers. BUF_/DO_A_/DO_B_ are LITERALS.
// VM_: 4 = vmcnt(4), 0 = vmcnt(0), -1 = none.
#define TILEBODY(BUF_, DO_A_, DO_B_, STEPA_, STEPB_, VM_)                      \
  {                                                                            \
    const u16* Ab = &As[BUF_][0];                                              \
    const u16* Bb = &Bs[BUF_][0];                                              \
    /* region A: all m0 reads + both B quads; stage A(t+1); MFMA m0n0,m0n1 */  \
    READ_AQ(af0, 0);                                                           \
    READ_BQ(bf0, 0);                                                           \
    READ_BQ(bf1, 1);                                                           \
    if (DO_A_) { gld16(aP, uA + ((BUF_) ^ 1) * 16384);                         \
                 gld16(aP + sA8, uA + ((BUF_) ^ 1) * 16384 + 512);             \
                 gld16(aP + sAh, uA + ((BUF_) ^ 1) * 16384 + 8192);            \
                 gld16(aP + sAh + sA8, uA + ((BUF_) ^ 1) * 16384 + 8192 + 512);\
                 aP += (STEPA_); }                                             \
    MFMA_Q2(0, 0, af0, bf0);                                                   \
    MFMA_Q2(0, 1, af0, bf1);                                                   \
    SBAR();                                                                    \
    /* region B: A quad1 reads; stage B(t+2); MFMA m1n1,m1n0 */                \
    READ_AQ(af1, 1);                                                           \
    if (DO_B_) { gld16(bP, uB + (BUF_) * 16384);                               \
                 gld16(bP + sB8, uB + (BUF_) * 16384 + 512);                   \
                 gld16(bP + sBh, uB + (BUF_) * 16384 + 8192);                  \
                 gld16(bP + sBh + sB8, uB + (BUF_) * 16384 + 8192 + 512);      \
                 bP += (STEPB_); }                                             \
    MFMA_Q2(1, 1, af1, bf1);                                                   \
    MFMA_Q2(1, 0, af1, bf0);                                                   \
    if ((VM_) == 4) asm volatile("s_waitcnt vmcnt(4)" ::: "memory");           \
    else if ((VM_) == 0) asm volatile("s_waitcnt vmcnt(0)" ::: "memory");      \
    SBAR();                                                                    \
  }

    // main loop: unconditional staging (valid while t+3 <= tot-1)
    int t = 0;
    for (; t + 3 < tot; t += 2) {
        const long long stA1 = (((t + 2) & kmask) != 0) ? 64 : dAtap;
        const long long stA2 = (((t + 3) & kmask) != 0) ? 64 : dAtap;
        const long long stB1 = (((t + 3) & kmask) != 0) ? 64 : dBtap;
        const long long stB2 = (((t + 4) & kmask) != 0) ? 64 : dBtap;
        TILEBODY(0, 1, 1, stA1, stB1, 4);
        TILEBODY(1, 1, 1, stA2, stB2, 4);
    }
    // epilogue pair: tile tot-2 (stage A(tot-1) only, full drain), tile tot-1
    TILEBODY(0, 1, 0, 0, 0, 0);
    TILEBODY(1, 0, 0, 0, 0, -1);
#undef READ_AQ
#undef READ_BQ
#undef MFMA_Q2
#undef TILEBODY

    if constexpr (OUTK == 4) {
        // GLU: a,b pairs in adjacent 16-col fragments; residual h_in via A operand.
        const float* bp = p.bias;
#pragma unroll
        for (int m = 0; m < 8; ++m) {
#pragma unroll
            for (int pr = 0; pr < 2; ++pr) {
                int ca = c0 + wcq * 64 + (2 * pr) * 16 + fr;
                int chan = (c0 >> 1) + wcq * 32 + pr * 16 + fr;
                float biasa = bp[ca], biasb = bp[ca + 16];
#pragma unroll
                for (int r = 0; r < 4; ++r) {
                    int row = n0 + wr * 128 + m * 16 + fq * 4 + r;
                    float a = acc[m][2 * pr][r] + biasa;
                    float bq = acc[m][2 * pr + 1][r] + biasb;
                    float sig = 1.f / (1.f + __expf(-bq));
                    float h = bf2f(Abase[(long long)row * lda + chan]);
                    ((u16*)p.out)[(long long)bz * p.o_bstride + (long long)row * p.ldc + chan]
                        = f2bf((h + a * sig) * SQRT_HALF_F);
                }
            }
        }
        return;
    } else if constexpr (OUTK == 2) {
        // f32 transposed store [col][ldc]+row, col-masked, col-bias
        const float* bias = p.bias + (long long)bz * p.bias_bstride;
#pragma unroll
        for (int m = 0; m < 8; ++m) {
#pragma unroll
            for (int n = 0; n < 4; ++n) {
                int col = c0 + wcq * 64 + n * 16 + fr;
                if (col >= p.store_ncols) continue;
                float cb = bias[col];
#pragma unroll
                for (int r = 0; r < 4; ++r) {
                    int row = n0 + wr * 128 + m * 16 + fq * 4 + r;
                    ((float*)p.out)[(long long)bz * p.o_bstride + (long long)col * p.ldc + row]
                        = acc[m][n][r] * p.scale + cb;
                }
            }
        }
        return;
    } else {
        const float* bias = p.bias ? p.bias + (long long)bz * p.bias_bstride : nullptr;
#pragma unroll
        for (int m = 0; m < 8; ++m) {
#pragma unroll
            for (int n = 0; n < 4; ++n) {
                int col = c0 + wcq * 64 + n * 16 + fr;
                float cb = (OUTK == 1 && bias) ? bias[col] : 0.f;
#pragma unroll
                for (int r = 0; r < 4; ++r) {
                    int row = n0 + wr * 128 + m * 16 + fq * 4 + r;
                    float v = acc[m][n][r] * p.scale + cb;
                    if (OUTK == 5) v += bias[row];
                    ((u16*)p.out)[(long long)bz * p.o_bstride + (long long)row * p.ldc + col]
                        = f2bf(v);
                }
            }
        }
    }
}

// ---------------- elementwise / helper kernels ----------------

__global__ void cvt_glu(const float* src, u16* dst) {
    long long t = (long long)blockIdx.x * blockDim.x + threadIdx.x;
    const long long total = 8LL * 5 * 1024 * 512;
    if (t >= total) return;
    int i = (int)(t % 512); long long r = t / 512;
    int g = (int)(r % 1024); r /= 1024;
    int k = (int)(r % 5); int l = (int)(r / 5);
    int o = glu_perm(g);
    dst[t] = f2bf(src[(((long long)l * 1024 + o) * 512 + i) * 5 + k]);
}

__global__ void perm_bias(const float* gb, float* biasP) {
    int t = blockIdx.x * 256 + threadIdx.x;
    if (t >= 8 * 1024) return;
    int g = t & 1023, l = t >> 10;
    biasP[t] = gb[l * 1024 + glu_perm(g)];
}

__global__ void cvt_pad(const float* src, u16* dst, int Os, int Is, int Od, int Id) {
    long long t = (long long)blockIdx.x * blockDim.x + threadIdx.x;
    if (t >= (long long)Od * Id) return;
    int i = (int)(t % Id); int o = (int)(t / Id);
    float v = (o < Os && i < Is) ? src[(long long)o * Is + i] : 0.f;
    dst[t] = f2bf(v);
}

// src [b][Csrc][Len] f32 -> dst [b][Len][Cdst] bf16 (zero-pad channels)
__global__ void transpose_in(const float* src, u16* dst, int Csrc, int Cdst, int Len) {
    __shared__ float tile[32][33];
    int b = blockIdx.z;
    int n0 = blockIdx.x * 32, c0 = blockIdx.y * 32;
    int tx = threadIdx.x, ty = threadIdx.y;
    int c = c0 + ty, n = n0 + tx;
    float v = 0.f;
    if (c < Csrc) v = src[((long long)b * Csrc + c) * Len + n];
    tile[ty][tx] = v;
    __syncthreads();
    dst[((long long)b * Len + (n0 + ty)) * Cdst + (c0 + tx)] = f2bf(tile[tx][ty]);
}

__global__ void zero_pads(u16* h) {
    long long t = (long long)blockIdx.x * blockDim.x + threadIdx.x;
    const long long total = (long long)BB * 128 * 512;
    if (t >= total) return;
    int c = (int)(t % 512); long long r = t / 512;
    int rr = (int)(r % 128); int b = (int)(r / 128);
    int row = rr < HPAD ? rr : (HROWS - 128 + rr);
    h[((long long)b * HROWS + row) * 512 + c] = 0;
}

__global__ void prebias_kernel(const float* ct, const float* wcpre, const float* wpre,
                               const float* bpre, float* qbias) {
    __shared__ float s[240];
    int b = blockIdx.x; int tid = threadIdx.x;
    if (tid < 240) {
        float a = 0.f;
        for (int c = 0; c < 8; ++c) a += ct[b * 8 + c] * wcpre[c * 240 + tid];
        s[tid] = a;
    }
    __syncthreads();
    for (int o = tid; o < 512; o += 256) {
        float a = bpre[o];
        for (int d0 = 0; d0 < 240; ++d0) a += wpre[o * 240 + d0] * s[d0];
        qbias[b * 512 + o] = a;
    }
}

__global__ void postbias_kernel(const float* ct, const float* wcpost, const float* wpost,
                                const float* bpost, float* ybias) {
    __shared__ float s[1024];
    int b = blockIdx.x; int tid = threadIdx.x;
    for (int e = tid; e < 1024; e += 256) {
        float a = 0.f;
        for (int c = 0; c < 8; ++c) a += ct[b * 8 + c] * wcpost[c * 1024 + e];
        s[e] = a;
    }
    __syncthreads();
    if (tid < 240) {
        float a = bpost[tid];
        for (int e = 0; e < 1024; ++e) a += wpost[tid * 1024 + e] * s[e];
        ybias[b * 240 + tid] = a;
    }
}

// One wave per (b,t): read bf16 score row, softmax, write normalized bf16 AT row.
__global__ __launch_bounds__(256)
void softmax_rows(const u16* St, u16* AT) {
    int b = blockIdx.y;
    int t = blockIdx.x * 4 + (threadIdx.x >> 6);
    int lane = threadIdx.x & 63;
    const u16* row = St + ((long long)b * TT + t) * NN;
    short8 v[4];
#pragma unroll
    for (int i = 0; i < 4; ++i) v[i] = ((const short8*)row)[i * 64 + lane];
    float f[32];
#pragma unroll
    for (int i = 0; i < 4; ++i)
#pragma unroll
        for (int j = 0; j < 8; ++j) f[i * 8 + j] = bf2f((u16)v[i][j]);
    float m = -3.4e38f;
#pragma unroll
    for (int i = 0; i < 32; ++i) m = fmaxf(m, f[i]);
#pragma unroll
    for (int s = 1; s < 64; s <<= 1) m = fmaxf(m, __shfl_xor(m, s, 64));
    float sum = 0.f;
#pragma unroll
    for (int i = 0; i < 32; ++i) { f[i] = __expf(f[i] - m); sum += f[i]; }
#pragma unroll
    for (int s = 1; s < 64; s <<= 1) sum += __shfl_xor(sum, s, 64);
    float li = 1.f / sum;
    u16* atrow = AT + ((long long)b * TT + t) * NN;
#pragma unroll
    for (int i = 0; i < 4; ++i) {
        short8 pk;
#pragma unroll
        for (int j = 0; j < 8; ++j) pk[j] = (short)f2bf(f[i * 8 + j] * li);
        ((short8*)atrow)[i * 64 + lane] = pk;
    }
}

// AT bf16 [b][t][n] -> A f32 [b][n][t] (final output region)
__global__ void transpose_out(const u16* AT, float* A) {
    __shared__ float tile[32][33];
    int b = blockIdx.z;
    int n0 = blockIdx.x * 32, t0 = blockIdx.y * 32;
    int tx = threadIdx.x, ty = threadIdx.y;
#pragma unroll
    for (int k = 0; k < 4; ++k) {
        int t = t0 + ty + k * 8;
        tile[ty + k * 8][tx] = bf2f(AT[((long long)b * TT + t) * NN + n0 + tx]);
    }
    __syncthreads();
#pragma unroll
    for (int k = 0; k < 4; ++k) {
        int n = n0 + ty + k * 8;
        A[((long long)b * NN + n) * TT + t0 + tx] = tile[tx][ty + k * 8];
    }
}

// ---------------- host orchestration ----------------

extern "C" void kernel_launch(void* const* d_in, const int* in_sizes, int n_in,
                              void* d_out, int out_size, void* d_ws, size_t ws_size,
                              hipStream_t stream) {
    const float* in_s        = (const float*)d_in[0];
    const float* in_t        = (const float*)d_in[1];
    const float* c_t         = (const float*)d_in[2];
    const float* enc_start_w = (const float*)d_in[3];
    const float* enc_start_b = (const float*)d_in[4];
    const float* glu_w       = (const float*)d_in[5];
    const float* glu_b       = (const float*)d_in[6];
    const float* enc_end_w   = (const float*)d_in[7];
    const float* enc_end_b   = (const float*)d_in[8];
    const float* wc_pre      = (const float*)d_in[9];
    const float* w_pre       = (const float*)d_in[10];
    const float* b_pre       = (const float*)d_in[11];
    const float* wc_post     = (const float*)d_in[12];
    const float* w_post      = (const float*)d_in[13];
    const float* b_post      = (const float*)d_in[14];

    // workspace layout
    char* w = (char*)d_ws;
    u16* wglu   = (u16*)w; w += 8LL * 5 * 1024 * 512 * 2;
    u16* wstart = (u16*)w; w += 512LL * 256 * 2;
    u16* wend   = (u16*)w; w += 1024LL * 512 * 2;
    u16* wpre   = (u16*)w; w += 512LL * 256 * 2;
    u16* wpost  = (u16*)w; w += 256LL * 1024 * 2;
    u16* XS     = (u16*)w; w += (long long)BB * NN * 256 * 2;
    u16* XT     = (u16*)w; w += (long long)BB * TT * 256 * 2;
    u16* h0     = (u16*)w; w += (long long)BB * HROWS * 512 * 2;
    u16* h1     = (u16*)w; w += (long long)BB * HROWS * 512 * 2;
    u16* Kb     = (u16*)w; w += (long long)BB * NN * 512 * 2;
    u16* Vb     = (u16*)w; w += (long long)BB * 512 * NN * 2;
    u16* Rc     = (u16*)w; w += (long long)BB * TT * 1024 * 2;
    u16* ATb    = (u16*)w; w += (long long)BB * TT * NN * 2;
    float* qbias = (float*)w; w += 16LL * 512 * 4;
    float* ybias = (float*)w; w += 16LL * 256 * 4;
    float* biasP = (float*)w; w += 8LL * 1024 * 4;
    if ((size_t)(w - (char*)d_ws) > ws_size) return;  // insufficient scratch — bail

    float* yout = (float*)d_out;
    float* Areg = yout + Y_SIZE;       // final A f32 [b][n][t]
    u16* Sbf = (u16*)Areg;             // transient bf16 scores [b][t][n]

    // ---- conversions / setup ----
    cvt_glu<<<(8LL * 5 * 1024 * 512 + 255) / 256, 256, 0, stream>>>(glu_w, wglu);
    perm_bias<<<(8 * 1024 + 255) / 256, 256, 0, stream>>>(glu_b, biasP);
    cvt_pad<<<(512 * 256 + 255) / 256, 256, 0, stream>>>(enc_start_w, wstart, 512, 240, 512, 256);
    cvt_pad<<<(1024 * 512 + 255) / 256, 256, 0, stream>>>(enc_end_w, wend, 1024, 512, 1024, 512);
    cvt_pad<<<(512 * 256 + 255) / 256, 256, 0, stream>>>(w_pre, wpre, 512, 240, 512, 256);
    cvt_pad<<<(256 * 1024 + 255) / 256, 256, 0, stream>>>(w_post, wpost, 240, 1024, 256, 1024);
    transpose_in<<<dim3(NN / 32, 256 / 32, BB), dim3(32, 32), 0, stream>>>(in_s, XS, 240, 256, NN);
    transpose_in<<<dim3(TT / 32, 256 / 32, BB), dim3(32, 32), 0, stream>>>(in_t, XT, 240, 256, TT);
    zero_pads<<<((long long)BB * 128 * 512 + 255) / 256, 256, 0, stream>>>(h0);
    zero_pads<<<((long long)BB * 128 * 512 + 255) / 256, 256, 0, stream>>>(h1);
    prebias_kernel<<<16, 256, 0, stream>>>(c_t, wc_pre, w_pre, b_pre, qbias);
    postbias_kernel<<<16, 256, 0, stream>>>(c_t, wc_post, w_post, b_post, ybias);

    // ---- enc_start: XS[2048][256] x wstart[512][256] -> h0 bf16 [n][512] ----
    {
        GemmP p{}; p.A = XS; p.a_bstride = (long long)NN * 256; p.lda = 256;
        p.Bw = wstart; p.b_bstride = 0; p.b_tapstride = 0; p.ldb = 256;
        p.ntaps = 1; p.shift0 = 0; p.dshift = 0; p.Kt = 256; p.ks_log2 = 2;
        p.out = h0 + HPAD * 512; p.o_bstride = (long long)HROWS * 512; p.ldc = 512;
        p.bias = enc_start_b; p.bias_bstride = 0; p.scale = 1.f; p.store_ncols = 512;
        gemm256<1><<<8 * 2 * 16, 512, 0, stream>>>(p, 8, 2);
    }

    // ---- 8 GLU blocks (fused epilogue) ----
    const int dils[8] = {1, 3, 9, 27, 1, 3, 9, 27};
    u16* hin = h0; u16* hout = h1;
    for (int l = 0; l < 8; ++l) {
        GemmP q{}; q.A = hin + HPAD * 512; q.a_bstride = (long long)HROWS * 512; q.lda = 512;
        q.Bw = wglu + (long long)l * 5 * 1024 * 512; q.b_bstride = 0;
        q.b_tapstride = 1024LL * 512; q.ldb = 512;
        q.ntaps = 5; q.shift0 = -2 * dils[l]; q.dshift = dils[l]; q.Kt = 512; q.ks_log2 = 3;
        q.out = hout + HPAD * 512; q.o_bstride = (long long)HROWS * 512; q.ldc = 512;
        q.bias = biasP + l * 1024; q.bias_bstride = 0; q.scale = 1.f; q.store_ncols = 1024;
        gemm256<4><<<8 * 4 * 16, 512, 0, stream>>>(q, 8, 4);
        u16* tmp = hin; hin = hout; hout = tmp;
    }

    // ---- enc_end K: h[n][512] x wend_K[512][512] -> Kb bf16 [n][512] ----
    {
        GemmP p{}; p.A = hin + HPAD * 512; p.a_bstride = (long long)HROWS * 512; p.lda = 512;
        p.Bw = wend; p.b_bstride = 0; p.b_tapstride = 0; p.ldb = 512;
        p.ntaps = 1; p.shift0 = 0; p.dshift = 0; p.Kt = 512; p.ks_log2 = 3;
        p.out = Kb; p.o_bstride = (long long)NN * 512; p.ldc = 512;
        p.bias = enc_end_b; p.bias_bstride = 0; p.scale = 1.f; p.store_ncols = 512;
        gemm256<1><<<8 * 2 * 16, 512, 0, stream>>>(p, 8, 2);
    }
    // ---- enc_end V (operand-swapped): Vb[d][n] = wend_V[d][k] · h[n][k], row-bias ----
    {
        GemmP p{}; p.A = wend + 512LL * 512; p.a_bstride = 0; p.lda = 512;
        p.Bw = hin + HPAD * 512; p.b_bstride = (long long)HROWS * 512; p.b_tapstride = 0; p.ldb = 512;
        p.ntaps = 1; p.shift0 = 0; p.dshift = 0; p.Kt = 512; p.ks_log2 = 3;
        p.out = Vb; p.o_bstride = 512LL * NN; p.ldc = NN;
        p.bias = enc_end_b + 512; p.bias_bstride = 0; p.scale = 1.f; p.store_ncols = NN;
        gemm256<5><<<2 * 8 * 16, 512, 0, stream>>>(p, 2, 8);
    }

    // ---- pre-decoder: Q into Rc columns 512..1023 ----
    {
        GemmP p{}; p.A = XT; p.a_bstride = (long long)TT * 256; p.lda = 256;
        p.Bw = wpre; p.b_bstride = 0; p.b_tapstride = 0; p.ldb = 256;
        p.ntaps = 1; p.shift0 = 0; p.dshift = 0; p.Kt = 256; p.ks_log2 = 2;
        p.out = Rc + 512; p.o_bstride = (long long)TT * 1024; p.ldc = 1024;
        p.bias = qbias; p.bias_bstride = 512; p.scale = 1.f; p.store_ncols = 512;
        gemm256<1><<<8 * 2 * 16, 512, 0, stream>>>(p, 8, 2);
    }

    // ---- scores: St[t][n] = Q[t]·K[n] / sqrt(d), bf16 into Sbf ----
    {
        GemmP p{}; p.A = Rc + 512; p.a_bstride = (long long)TT * 1024; p.lda = 1024;
        p.Bw = Kb; p.b_bstride = (long long)NN * 512; p.b_tapstride = 0; p.ldb = 512;
        p.ntaps = 1; p.shift0 = 0; p.dshift = 0; p.Kt = 512; p.ks_log2 = 3;
        p.out = Sbf; p.o_bstride = (long long)TT * NN; p.ldc = NN;
        p.bias = nullptr; p.bias_bstride = 0; p.scale = 0.04419417382415922f; // 1/sqrt(512)
        p.store_ncols = NN;
        gemm256<1><<<8 * 8 * 16, 512, 0, stream>>>(p, 8, 8);
    }

    // ---- softmax over n (contiguous), normalized AT bf16 ----
    softmax_rows<<<dim3(TT / 4, BB), 256, 0, stream>>>(Sbf, ATb);
    // ---- AT -> final A f32 [n][t] (overwrites dead Sbf region) ----
    transpose_out<<<dim3(NN / 32, TT / 32, BB), dim3(32, 8), 0, stream>>>(ATb, Areg);

    // ---- R = V x A  (C[t][d] = sum_n AT[t][n] * V[d][n]) into Rc cols 0..511 ----
    {
        GemmP p{}; p.A = ATb; p.a_bstride = (long long)TT * NN; p.lda = NN;
        p.Bw = Vb; p.b_bstride = 512LL * NN; p.b_tapstride = 0; p.ldb = NN;
        p.ntaps = 1; p.shift0 = 0; p.dshift = 0; p.Kt = NN; p.ks_log2 = 5;
        p.out = Rc; p.o_bstride = (long long)TT * 1024; p.ldc = 1024;
        p.bias = nullptr; p.bias_bstride = 0; p.scale = 1.f; p.store_ncols = 512;
        gemm256<1><<<8 * 2 * 16, 512, 0, stream>>>(p, 8, 2);
    }

    // ---- post-decoder: Rc[t][1024] x wpost -> y f32 [b][240][t] (transposed store) ----
    {
        GemmP p{}; p.A = Rc; p.a_bstride = (long long)TT * 1024; p.lda = 1024;
        p.Bw = wpost; p.b_bstride = 0; p.b_tapstride = 0; p.ldb = 1024;
        p.ntaps = 1; p.shift0 = 0; p.dshift = 0; p.Kt = 1024; p.ks_log2 = 4;
        p.out = yout; p.o_bstride = (long long)DIN * TT; p.ldc = TT;
        p.bias = ybias; p.bias_bstride = 240; p.scale = 1.f; p.store_ncols = 240;
        gemm256<2><<<8 * 1 * 16, 512, 0, stream>>>(p, 8, 1);
    }
}